// Round 4
// baseline (317.681 us; speedup 1.0000x reference)
//
#include <hip/hip_runtime.h>
#include <math.h>

#define EPSF 1e-12f

__device__ __forceinline__ float red16(float v) {
    v += __shfl_xor(v, 1, 16);
    v += __shfl_xor(v, 2, 16);
    v += __shfl_xor(v, 4, 16);
    v += __shfl_xor(v, 8, 16);
    return v;
}

__device__ __forceinline__ float red8(float v) {
    v += __shfl_xor(v, 1, 8);
    v += __shfl_xor(v, 2, 8);
    v += __shfl_xor(v, 4, 8);
    return v;
}

// branch-free tanh via hardware exp; exact at +/-inf limits
__device__ __forceinline__ float fast_tanh(float x) {
    return 1.0f - 2.0f / (__expf(2.0f * x) + 1.0f);
}

__device__ __forceinline__ float leaky(float x) {
    return x > 0.0f ? x : 0.01f * x;
}

// ---------------- per-node dot precompute: dot[n] = ent[n] . entT[n] ----------
__global__ __launch_bounds__(256) void precomp_dot(
    const float* __restrict__ ent, const float* __restrict__ entT,
    float* __restrict__ dot, int N) {
    int gid = blockIdx.x * 256 + threadIdx.x;
    int v = gid >> 4, lane = gid & 15;
    if (v >= N) return;
    const float4 a = *(const float4*)(ent  + (size_t)v * 64 + lane * 4);
    const float4 b = *(const float4*)(entT + (size_t)v * 64 + lane * 4);
    float d = red16(a.x*b.x + a.y*b.y + a.z*b.z + a.w*b.w);
    if (lane == 0) dot[v] = d;
}

// ---------------- CSR build (counting sort by dst) ----------------

__global__ __launch_bounds__(256) void count_deg(
    const int* __restrict__ dst, int* __restrict__ deg, int E) {
    int e = blockIdx.x * 256 + threadIdx.x;
    if (e < E) atomicAdd(&deg[dst[e]], 1);
}

__global__ __launch_bounds__(256) void scan_reduce(
    const int* __restrict__ deg, int* __restrict__ part, int N) {
    __shared__ int sh[256];
    int t = threadIdx.x, i = blockIdx.x * 256 + t;
    sh[t] = (i < N) ? deg[i] : 0;
    __syncthreads();
    for (int off = 128; off > 0; off >>= 1) {
        if (t < off) sh[t] += sh[t + off];
        __syncthreads();
    }
    if (t == 0) part[blockIdx.x] = sh[0];
}

__global__ __launch_bounds__(1024) void scan_part(int* __restrict__ part, int nb) {
    __shared__ int sh[1024];
    int t = threadIdx.x;
    int x = (t < nb) ? part[t] : 0;
    sh[t] = x;
    __syncthreads();
    for (int off = 1; off < 1024; off <<= 1) {
        int y = (t >= off) ? sh[t - off] : 0;
        __syncthreads();
        sh[t] += y;
        __syncthreads();
    }
    if (t < nb) part[t] = sh[t] - x;  // exclusive
}

__global__ __launch_bounds__(256) void scan_write(
    int* __restrict__ rowptr, const int* __restrict__ part, int N) {
    __shared__ int sh[256];
    int t = threadIdx.x, i = blockIdx.x * 256 + t;
    int x = (i < N) ? rowptr[i] : 0;
    sh[t] = x;
    __syncthreads();
    for (int off = 1; off < 256; off <<= 1) {
        int y = (t >= off) ? sh[t - off] : 0;
        __syncthreads();
        sh[t] += y;
        __syncthreads();
    }
    if (i < N) rowptr[i] = part[blockIdx.x] + sh[t] - x;  // exclusive scan
}

// After this, rowptr[v] = end(v); start(v) = (v ? rowptr[v-1] : 0).
// Packs (src, etype) into one int per CSR slot: src | (ety << 20).
__global__ __launch_bounds__(256) void scatter_edges(
    const int* __restrict__ src, const int* __restrict__ dst,
    const int* __restrict__ ety, int* __restrict__ rowptr,
    int* __restrict__ spk, int E) {
    int e = blockIdx.x * 256 + threadIdx.x;
    if (e < E) {
        int slot = atomicAdd(&rowptr[dst[e]], 1);
        spk[slot] = src[e] | (ety[e] << 20);
    }
}

// ------------- fused layer-0: att + softmax + message + bi-layer GEMV -------
// Gather phase: 16 lanes per dst node (16 nodes / 256-thread block).
// GEMV phase: same threads, node0 update via LDS-staged a/b vectors.
__global__ __launch_bounds__(256) void fused_l0(
    const int* __restrict__ rowptr, const int* __restrict__ spk,
    const float* __restrict__ ent, const float* __restrict__ dot,
    const float* __restrict__ relE, const float* __restrict__ relT,
    const float* __restrict__ W1, const float* __restrict__ b1,
    const float* __restrict__ W2, const float* __restrict__ b2,
    float* __restrict__ exatt, float* __restrict__ sinv,
    float* __restrict__ node1raw, float* __restrict__ out, int N) {
    __shared__ float al[16][68];  // stride 68: 16B-aligned rows, bank-offset 4
    __shared__ float bl[16][68];
    int t = threadIdx.x;
    int nv = t >> 4, lane = t & 15;
    int v = blockIdx.x * 16 + nv;

    if (v < N) {
        int s = v ? rowptr[v - 1] : 0;
        int epos = rowptr[v];
        const float4 he = *(const float4*)(ent + (size_t)v * 64 + lane * 4);
        float dh = dot[v];

        float4 macc = {0.f, 0.f, 0.f, 0.f};
        float sumex = 0.0f;

        for (int i = s; i < epos; ++i) {
            int pk = spk[i];
            int sv = pk & 0xFFFFF;
            int rv = pk >> 20;
            const float4 te = *(const float4*)(ent  + (size_t)sv * 64 + lane * 4);
            float sdt = dot[sv];
            const float4 rp = *(const float4*)(relT + rv * 64 + lane * 4);
            const float4 re = *(const float4*)(relE + rv * 64 + lane * 4);

            float4 mt, mh;
            mt.x = te.x + sdt * rp.x; mt.y = te.y + sdt * rp.y;
            mt.z = te.z + sdt * rp.z; mt.w = te.w + sdt * rp.w;
            mh.x = he.x + dh * rp.x;  mh.y = he.y + dh * rp.y;
            mh.z = he.z + dh * rp.z;  mh.w = he.w + dh * rp.w;

            float sst = red16(mt.x*mt.x + mt.y*mt.y + mt.z*mt.z + mt.w*mt.w);
            float ssh = red16(mh.x*mh.x + mh.y*mh.y + mh.z*mh.z + mh.w*mh.w);
            float it = 1.0f / fmaxf(sqrtf(sst), EPSF);
            float ih = 1.0f / fmaxf(sqrtf(ssh), EPSF);

            float tx = fast_tanh(mh.x * ih + re.x);
            float ty = fast_tanh(mh.y * ih + re.y);
            float tz = fast_tanh(mh.z * ih + re.z);
            float tw = fast_tanh(mh.w * ih + re.w);

            float att = it * red16(mt.x*tx + mt.y*ty + mt.z*tz + mt.w*tw);
            // softmax shift-invariant; |att| <= 8 so exp is safe without max-sub
            float ex = __expf(att);               // identical across the 16 lanes
            if (lane == 0) exatt[i] = ex;         // raw; consumers scale by sinv
            sumex += ex;
            macc.x += ex * te.x; macc.y += ex * te.y;
            macc.z += ex * te.z; macc.w += ex * te.w;
        }

        float inv = 1.0f / fmaxf(sumex, EPSF);
        if (lane == 0) sinv[v] = inv;
        macc.x *= inv; macc.y *= inv; macc.z *= inv; macc.w *= inv;

        // out cols 0..63 = ent_embed
        *(float4*)(out + (size_t)v * 112 + lane * 4) = he;

        float4 av, bv;
        av.x = he.x + macc.x; av.y = he.y + macc.y;
        av.z = he.z + macc.z; av.w = he.w + macc.w;
        bv.x = he.x * macc.x; bv.y = he.y * macc.y;
        bv.z = he.z * macc.z; bv.w = he.w * macc.w;
        *(float4*)&al[nv][lane * 4] = av;
        *(float4*)&bl[nv][lane * 4] = bv;
    }
    __syncthreads();
    if (v < N) {
        #pragma unroll
        for (int jo = 0; jo < 2; ++jo) {
            int j = lane + jo * 16;
            float acc1 = b1[j], acc2 = b2[j];
            #pragma unroll
            for (int d = 0; d < 64; d += 4) {
                float4 a4 = *(const float4*)&al[nv][d];
                float4 b4 = *(const float4*)&bl[nv][d];
                acc1 += a4.x * W1[(d+0)*32 + j] + a4.y * W1[(d+1)*32 + j]
                      + a4.z * W1[(d+2)*32 + j] + a4.w * W1[(d+3)*32 + j];
                acc2 += b4.x * W2[(d+0)*32 + j] + b4.y * W2[(d+1)*32 + j]
                      + b4.z * W2[(d+2)*32 + j] + b4.w * W2[(d+3)*32 + j];
            }
            node1raw[(size_t)v * 32 + j] = leaky(acc1) + leaky(acc2);
        }
    }
}

// ------------- fused layer-1: message gather + bi-layer GEMV + norms --------
// Gather: 8 lanes per node (32 nodes / block). Writes out cols 64..95
// (normalized node1) and 96..111 (final layer).
__global__ __launch_bounds__(256) void fused_l1(
    const int* __restrict__ rowptr, const int* __restrict__ spk,
    const float* __restrict__ exatt, const float* __restrict__ sinv,
    const float* __restrict__ node1raw,
    const float* __restrict__ W1, const float* __restrict__ b1,
    const float* __restrict__ W2, const float* __restrict__ b2,
    float* __restrict__ out, int N) {
    __shared__ float A[32][36];  // stride 36: 16B-aligned rows, bank-offset 4
    __shared__ float B[32][36];
    int t = threadIdx.x;
    int nv = t >> 3, lane = t & 7;
    int v = blockIdx.x * 32 + nv;

    if (v < N) {
        int s = v ? rowptr[v - 1] : 0;
        int epos = rowptr[v];
        float4 n = *(const float4*)(node1raw + (size_t)v * 32 + lane * 4);
        float4 acc = {0.f, 0.f, 0.f, 0.f};
        for (int i = s; i < epos; ++i) {
            float a = exatt[i];
            int sv = spk[i] & 0xFFFFF;
            const float4 x = *(const float4*)(node1raw + (size_t)sv * 32 + lane * 4);
            acc.x += a * x.x; acc.y += a * x.y;
            acc.z += a * x.z; acc.w += a * x.w;
        }
        float inv = sinv[v];
        acc.x *= inv; acc.y *= inv; acc.z *= inv; acc.w *= inv;

        // normalized node1 -> out cols 64..95
        float ss = red8(n.x*n.x + n.y*n.y + n.z*n.z + n.w*n.w);
        float inv1 = 1.0f / fmaxf(sqrtf(ss), EPSF);
        float4 nn = {n.x*inv1, n.y*inv1, n.z*inv1, n.w*inv1};
        *(float4*)(out + (size_t)v * 112 + 64 + lane * 4) = nn;

        float4 av = {n.x + acc.x, n.y + acc.y, n.z + acc.z, n.w + acc.w};
        float4 bv = {n.x * acc.x, n.y * acc.y, n.z * acc.z, n.w * acc.w};
        *(float4*)&A[nv][lane * 4] = av;
        *(float4*)&B[nv][lane * 4] = bv;
    }
    __syncthreads();
    if (v < N) {
        int j0 = lane * 2, j1 = j0 + 1;
        float a10 = b1[j0], a11 = b1[j1];
        float a20 = b2[j0], a21 = b2[j1];
        #pragma unroll
        for (int d = 0; d < 32; d += 4) {
            float4 a4 = *(const float4*)&A[nv][d];
            float4 b4 = *(const float4*)&B[nv][d];
            float2 w0 = *(const float2*)(W1 + (d+0)*16 + j0);
            float2 w1 = *(const float2*)(W1 + (d+1)*16 + j0);
            float2 w2 = *(const float2*)(W1 + (d+2)*16 + j0);
            float2 w3 = *(const float2*)(W1 + (d+3)*16 + j0);
            a10 += a4.x*w0.x + a4.y*w1.x + a4.z*w2.x + a4.w*w3.x;
            a11 += a4.x*w0.y + a4.y*w1.y + a4.z*w2.y + a4.w*w3.y;
            float2 u0 = *(const float2*)(W2 + (d+0)*16 + j0);
            float2 u1 = *(const float2*)(W2 + (d+1)*16 + j0);
            float2 u2 = *(const float2*)(W2 + (d+2)*16 + j0);
            float2 u3 = *(const float2*)(W2 + (d+3)*16 + j0);
            a20 += b4.x*u0.x + b4.y*u1.x + b4.z*u2.x + b4.w*u3.x;
            a21 += b4.x*u0.y + b4.y*u1.y + b4.z*u2.y + b4.w*u3.y;
        }
        float t0 = leaky(a10) + leaky(a20);
        float t1 = leaky(a11) + leaky(a21);
        float s2 = red8(t0*t0 + t1*t1);
        float inv2 = 1.0f / fmaxf(sqrtf(s2), EPSF);
        float2 o = {t0 * inv2, t1 * inv2};
        *(float2*)(out + (size_t)v * 112 + 96 + j0) = o;
    }
}

extern "C" void kernel_launch(void* const* d_in, const int* in_sizes, int n_in,
                              void* d_out, int out_size, void* d_ws, size_t ws_size,
                              hipStream_t stream) {
    const int*   src  = (const int*)d_in[0];
    const int*   dst  = (const int*)d_in[1];
    const int*   ety  = (const int*)d_in[2];
    const float* ent  = (const float*)d_in[3];
    const float* entT = (const float*)d_in[4];
    const float* relE = (const float*)d_in[5];
    const float* relT = (const float*)d_in[6];
    const float* W1_0 = (const float*)d_in[7];
    const float* b1_0 = (const float*)d_in[8];
    const float* W2_0 = (const float*)d_in[9];
    const float* b2_0 = (const float*)d_in[10];
    const float* W1_1 = (const float*)d_in[11];
    const float* b1_1 = (const float*)d_in[12];
    const float* W2_1 = (const float*)d_in[13];
    const float* b2_1 = (const float*)d_in[14];
    float* out = (float*)d_out;

    const int E = in_sizes[0];
    const int N = in_sizes[3] / 64;
    const int nb = (N + 255) / 256;  // scan blocks (must be <= 1024)

    auto al256 = [](size_t x) { return (x + 255) & ~(size_t)255; };
    char* ws = (char*)d_ws;
    size_t offExatt = 0;
    size_t offS     = al256(offExatt + (size_t)E * 4);
    size_t offDot   = al256(offS + (size_t)N * 4);
    size_t offRow   = al256(offDot + (size_t)N * 4);
    size_t offSpk   = al256(offRow + (size_t)N * 4);
    size_t offPart  = al256(offSpk + (size_t)E * 4);
    size_t offN1    = al256(offPart + (size_t)nb * 4);
    float* exatt    = (float*)(ws + offExatt);
    float* sinv     = (float*)(ws + offS);
    float* dot      = (float*)(ws + offDot);
    int*   rowptr   = (int*)(ws + offRow);
    int*   spk      = (int*)(ws + offSpk);
    int*   part     = (int*)(ws + offPart);
    float* node1raw = (float*)(ws + offN1);   // [N,32]

    // ---- CSR build + per-node dot ----
    hipMemsetAsync(rowptr, 0, (size_t)N * 4, stream);
    precomp_dot<<<(N * 16 + 255) / 256, 256, 0, stream>>>(ent, entT, dot, N);
    int blkE = (E + 255) / 256;
    count_deg<<<blkE, 256, 0, stream>>>(dst, rowptr, E);
    scan_reduce<<<nb, 256, 0, stream>>>(rowptr, part, N);
    scan_part<<<1, 1024, 0, stream>>>(part, nb);
    scan_write<<<nb, 256, 0, stream>>>(rowptr, part, N);
    scatter_edges<<<blkE, 256, 0, stream>>>(src, dst, ety, rowptr, spk, E);

    // ---- fused layer 0: attention + softmax + message + node update ----
    fused_l0<<<(N + 15) / 16, 256, 0, stream>>>(
        rowptr, spk, ent, dot, relE, relT,
        W1_0, b1_0, W2_0, b2_0, exatt, sinv, node1raw, out, N);

    // ---- fused layer 1: message + node update + norms ----
    fused_l1<<<(N + 31) / 32, 256, 0, stream>>>(
        rowptr, spk, exatt, sinv, node1raw,
        W1_1, b1_1, W2_1, b2_1, out, N);
}

// Round 5
// 287.652 us; speedup vs baseline: 1.1044x; 1.1044x over previous
//
#include <hip/hip_runtime.h>
#include <math.h>

#define EPSF 1e-12f

__device__ __forceinline__ float red16(float v) {
    v += __shfl_xor(v, 1, 16);
    v += __shfl_xor(v, 2, 16);
    v += __shfl_xor(v, 4, 16);
    v += __shfl_xor(v, 8, 16);
    return v;
}

__device__ __forceinline__ float red8(float v) {
    v += __shfl_xor(v, 1, 8);
    v += __shfl_xor(v, 2, 8);
    v += __shfl_xor(v, 4, 8);
    return v;
}

// branch-free tanh via hardware exp; exact at +/-inf limits
__device__ __forceinline__ float fast_tanh(float x) {
    return 1.0f - 2.0f / (__expf(2.0f * x) + 1.0f);
}

__device__ __forceinline__ float leaky(float x) {
    return x > 0.0f ? x : 0.01f * x;
}

// ---------------- per-node dot precompute: dot[n] = ent[n] . entT[n] ----------
__global__ __launch_bounds__(256) void precomp_dot(
    const float* __restrict__ ent, const float* __restrict__ entT,
    float* __restrict__ dot, int N) {
    int gid = blockIdx.x * 256 + threadIdx.x;
    int v = gid >> 4, lane = gid & 15;
    if (v >= N) return;
    const float4 a = *(const float4*)(ent  + (size_t)v * 64 + lane * 4);
    const float4 b = *(const float4*)(entT + (size_t)v * 64 + lane * 4);
    float d = red16(a.x*b.x + a.y*b.y + a.z*b.z + a.w*b.w);
    if (lane == 0) dot[v] = d;
}

// ---------------- CSR build (counting sort by dst) ----------------

__global__ __launch_bounds__(256) void count_deg(
    const int* __restrict__ dst, int* __restrict__ deg, int E) {
    int e = blockIdx.x * 256 + threadIdx.x;
    if (e < E) atomicAdd(&deg[dst[e]], 1);
}

__global__ __launch_bounds__(256) void scan_reduce(
    const int* __restrict__ deg, int* __restrict__ part, int N) {
    __shared__ int sh[256];
    int t = threadIdx.x, i = blockIdx.x * 256 + t;
    sh[t] = (i < N) ? deg[i] : 0;
    __syncthreads();
    for (int off = 128; off > 0; off >>= 1) {
        if (t < off) sh[t] += sh[t + off];
        __syncthreads();
    }
    if (t == 0) part[blockIdx.x] = sh[0];
}

__global__ __launch_bounds__(1024) void scan_part(int* __restrict__ part, int nb) {
    __shared__ int sh[1024];
    int t = threadIdx.x;
    int x = (t < nb) ? part[t] : 0;
    sh[t] = x;
    __syncthreads();
    for (int off = 1; off < 1024; off <<= 1) {
        int y = (t >= off) ? sh[t - off] : 0;
        __syncthreads();
        sh[t] += y;
        __syncthreads();
    }
    if (t < nb) part[t] = sh[t] - x;  // exclusive
}

__global__ __launch_bounds__(256) void scan_write(
    int* __restrict__ rowptr, const int* __restrict__ part, int N) {
    __shared__ int sh[256];
    int t = threadIdx.x, i = blockIdx.x * 256 + t;
    int x = (i < N) ? rowptr[i] : 0;
    sh[t] = x;
    __syncthreads();
    for (int off = 1; off < 256; off <<= 1) {
        int y = (t >= off) ? sh[t - off] : 0;
        __syncthreads();
        sh[t] += y;
        __syncthreads();
    }
    if (i < N) rowptr[i] = part[blockIdx.x] + sh[t] - x;  // exclusive scan
}

// After this, rowptr[v] = end(v); start(v) = (v ? rowptr[v-1] : 0).
// Packs (src, etype) into one int per CSR slot: src | (ety << 20).
__global__ __launch_bounds__(256) void scatter_edges(
    const int* __restrict__ src, const int* __restrict__ dst,
    const int* __restrict__ ety, int* __restrict__ rowptr,
    int* __restrict__ spk, int E) {
    int e = blockIdx.x * 256 + threadIdx.x;
    if (e < E) {
        int slot = atomicAdd(&rowptr[dst[e]], 1);
        spk[slot] = src[e] | (ety[e] << 20);
    }
}

// ------------- fused layer-0: att + softmax + message + bi-layer GEMV -------
// 16 lanes per dst node (16 nodes / 256-thread block). Edge loop is
// software-pipelined (pk chunk preload + shfl broadcast, gather 1 ahead).
// NO block barrier between gather and GEMV: the LDS a/b rows for node nv are
// written and read by the same 16 lanes of the same wave (wave-synchronous).
__global__ __launch_bounds__(256) void fused_l0(
    const int* __restrict__ rowptr, const int* __restrict__ spk,
    const float* __restrict__ ent, const float* __restrict__ dot,
    const float* __restrict__ relE, const float* __restrict__ relT,
    const float* __restrict__ W1, const float* __restrict__ b1,
    const float* __restrict__ W2, const float* __restrict__ b2,
    float* __restrict__ exatt, float* __restrict__ sinv,
    float* __restrict__ node1raw, float* __restrict__ out, int N) {
    __shared__ float al[16][68];  // stride 68: 16B-aligned rows, bank offset 4
    __shared__ float bl[16][68];
    __shared__ float rT[16][68];  // rel tables staged in LDS (16 rels x 64)
    __shared__ float rE[16][68];
    int t = threadIdx.x;

    {   // stage rel tables: 256 threads = 16 rows x 16 quads
        int r = t >> 4, c = (t & 15) * 4;
        *(float4*)&rT[r][c] = *(const float4*)(relT + r * 64 + c);
        *(float4*)&rE[r][c] = *(const float4*)(relE + r * 64 + c);
    }
    __syncthreads();  // the only block barrier

    int nv = t >> 4, lane = t & 15;
    int v = blockIdx.x * 16 + nv;
    if (v >= N) return;

    int s = v ? rowptr[v - 1] : 0;
    int epos = rowptr[v];
    const float4 he = *(const float4*)(ent + (size_t)v * 64 + lane * 4);
    float dh = dot[v];

    float4 macc = {0.f, 0.f, 0.f, 0.f};
    float sumex = 0.0f;

    for (int base = s; base < epos; base += 16) {
        int rem = epos - base;
        int cnt = rem < 16 ? rem : 16;
        int mypk = (lane < rem) ? spk[base + lane] : 0;  // one coalesced load
        // prime the pipeline with edge k=0
        int pkc = __shfl(mypk, 0, 16);
        int svc = pkc & 0xFFFFF;
        float4 tec = *(const float4*)(ent + (size_t)svc * 64 + lane * 4);
        float sdtc = dot[svc];
        for (int k = 0; k < cnt; ++k) {
            float4 te = tec;
            float sdt = sdtc;
            int rv = (pkc >> 20) & 15;
            int i = base + k;
            if (k + 1 < cnt) {  // prefetch edge k+1 while computing edge k
                pkc = __shfl(mypk, k + 1, 16);
                int svn = pkc & 0xFFFFF;
                tec = *(const float4*)(ent + (size_t)svn * 64 + lane * 4);
                sdtc = dot[svn];
            }
            const float4 rp = *(const float4*)&rT[rv][lane * 4];
            const float4 re = *(const float4*)&rE[rv][lane * 4];

            float4 mt, mh;
            mt.x = te.x + sdt * rp.x; mt.y = te.y + sdt * rp.y;
            mt.z = te.z + sdt * rp.z; mt.w = te.w + sdt * rp.w;
            mh.x = he.x + dh * rp.x;  mh.y = he.y + dh * rp.y;
            mh.z = he.z + dh * rp.z;  mh.w = he.w + dh * rp.w;

            float sst = red16(mt.x*mt.x + mt.y*mt.y + mt.z*mt.z + mt.w*mt.w);
            float ssh = red16(mh.x*mh.x + mh.y*mh.y + mh.z*mh.z + mh.w*mh.w);
            float it = 1.0f / fmaxf(sqrtf(sst), EPSF);
            float ih = 1.0f / fmaxf(sqrtf(ssh), EPSF);

            float tx = fast_tanh(mh.x * ih + re.x);
            float ty = fast_tanh(mh.y * ih + re.y);
            float tz = fast_tanh(mh.z * ih + re.z);
            float tw = fast_tanh(mh.w * ih + re.w);

            float att = it * red16(mt.x*tx + mt.y*ty + mt.z*tz + mt.w*tw);
            // softmax shift-invariant; |att| <= 8 so exp is safe without max-sub
            float ex = __expf(att);               // identical across the 16 lanes
            if (lane == 0) exatt[i] = ex;         // raw; consumers scale by sinv
            sumex += ex;
            macc.x += ex * te.x; macc.y += ex * te.y;
            macc.z += ex * te.z; macc.w += ex * te.w;
        }
    }

    float inv = 1.0f / fmaxf(sumex, EPSF);
    if (lane == 0) sinv[v] = inv;
    macc.x *= inv; macc.y *= inv; macc.z *= inv; macc.w *= inv;

    // out cols 0..63 = ent_embed
    *(float4*)(out + (size_t)v * 112 + lane * 4) = he;

    float4 av, bv;
    av.x = he.x + macc.x; av.y = he.y + macc.y;
    av.z = he.z + macc.z; av.w = he.w + macc.w;
    bv.x = he.x * macc.x; bv.y = he.y * macc.y;
    bv.z = he.z * macc.z; bv.w = he.w * macc.w;
    *(float4*)&al[nv][lane * 4] = av;
    *(float4*)&bl[nv][lane * 4] = bv;
    // no __syncthreads: same 16 lanes (same wave) read these rows below

    #pragma unroll
    for (int jo = 0; jo < 2; ++jo) {
        int j = lane + jo * 16;
        float acc1 = b1[j], acc2 = b2[j];
        #pragma unroll
        for (int d = 0; d < 64; d += 4) {
            float4 a4 = *(const float4*)&al[nv][d];
            float4 b4 = *(const float4*)&bl[nv][d];
            acc1 += a4.x * W1[(d+0)*32 + j] + a4.y * W1[(d+1)*32 + j]
                  + a4.z * W1[(d+2)*32 + j] + a4.w * W1[(d+3)*32 + j];
            acc2 += b4.x * W2[(d+0)*32 + j] + b4.y * W2[(d+1)*32 + j]
                  + b4.z * W2[(d+2)*32 + j] + b4.w * W2[(d+3)*32 + j];
        }
        node1raw[(size_t)v * 32 + j] = leaky(acc1) + leaky(acc2);
    }
}

// ------------- fused layer-1: message gather + bi-layer GEMV + norms --------
// 8 lanes per node (32 nodes / block). Same pipelining; no block barrier.
__global__ __launch_bounds__(256) void fused_l1(
    const int* __restrict__ rowptr, const int* __restrict__ spk,
    const float* __restrict__ exatt, const float* __restrict__ sinv,
    const float* __restrict__ node1raw,
    const float* __restrict__ W1, const float* __restrict__ b1,
    const float* __restrict__ W2, const float* __restrict__ b2,
    float* __restrict__ out, int N) {
    __shared__ float A[32][36];  // stride 36: 16B-aligned rows, bank offset 4
    __shared__ float B[32][36];
    int t = threadIdx.x;
    int nv = t >> 3, lane = t & 7;
    int v = blockIdx.x * 32 + nv;
    if (v >= N) return;

    int s = v ? rowptr[v - 1] : 0;
    int epos = rowptr[v];
    float4 n = *(const float4*)(node1raw + (size_t)v * 32 + lane * 4);
    float4 acc = {0.f, 0.f, 0.f, 0.f};

    for (int base = s; base < epos; base += 8) {
        int rem = epos - base;
        int cnt = rem < 8 ? rem : 8;
        int   mypk = (lane < rem) ? spk[base + lane] : 0;
        float myex = (lane < rem) ? exatt[base + lane] : 0.f;
        int pkc = __shfl(mypk, 0, 8);
        float4 xc = *(const float4*)(node1raw + (size_t)(pkc & 0xFFFFF) * 32 + lane * 4);
        for (int k = 0; k < cnt; ++k) {
            float4 x = xc;
            float a = __shfl(myex, k, 8);
            if (k + 1 < cnt) {
                pkc = __shfl(mypk, k + 1, 8);
                xc = *(const float4*)(node1raw + (size_t)(pkc & 0xFFFFF) * 32 + lane * 4);
            }
            acc.x += a * x.x; acc.y += a * x.y;
            acc.z += a * x.z; acc.w += a * x.w;
        }
    }
    float inv = sinv[v];
    acc.x *= inv; acc.y *= inv; acc.z *= inv; acc.w *= inv;

    // normalized node1 -> out cols 64..95
    float ss = red8(n.x*n.x + n.y*n.y + n.z*n.z + n.w*n.w);
    float inv1 = 1.0f / fmaxf(sqrtf(ss), EPSF);
    float4 nn = {n.x*inv1, n.y*inv1, n.z*inv1, n.w*inv1};
    *(float4*)(out + (size_t)v * 112 + 64 + lane * 4) = nn;

    float4 av = {n.x + acc.x, n.y + acc.y, n.z + acc.z, n.w + acc.w};
    float4 bv = {n.x * acc.x, n.y * acc.y, n.z * acc.z, n.w * acc.w};
    *(float4*)&A[nv][lane * 4] = av;
    *(float4*)&B[nv][lane * 4] = bv;
    // no __syncthreads: same 8 lanes (same wave) read these rows below

    int j0 = lane * 2;
    float a10 = b1[j0], a11 = b1[j0 + 1];
    float a20 = b2[j0], a21 = b2[j0 + 1];
    #pragma unroll
    for (int d = 0; d < 32; d += 4) {
        float4 a4 = *(const float4*)&A[nv][d];
        float4 b4 = *(const float4*)&B[nv][d];
        float2 w0 = *(const float2*)(W1 + (d+0)*16 + j0);
        float2 w1 = *(const float2*)(W1 + (d+1)*16 + j0);
        float2 w2 = *(const float2*)(W1 + (d+2)*16 + j0);
        float2 w3 = *(const float2*)(W1 + (d+3)*16 + j0);
        a10 += a4.x*w0.x + a4.y*w1.x + a4.z*w2.x + a4.w*w3.x;
        a11 += a4.x*w0.y + a4.y*w1.y + a4.z*w2.y + a4.w*w3.y;
        float2 u0 = *(const float2*)(W2 + (d+0)*16 + j0);
        float2 u1 = *(const float2*)(W2 + (d+1)*16 + j0);
        float2 u2 = *(const float2*)(W2 + (d+2)*16 + j0);
        float2 u3 = *(const float2*)(W2 + (d+3)*16 + j0);
        a20 += b4.x*u0.x + b4.y*u1.x + b4.z*u2.x + b4.w*u3.x;
        a21 += b4.x*u0.y + b4.y*u1.y + b4.z*u2.y + b4.w*u3.y;
    }
    float t0 = leaky(a10) + leaky(a20);
    float t1 = leaky(a11) + leaky(a21);
    float s2 = red8(t0*t0 + t1*t1);
    float inv2 = 1.0f / fmaxf(sqrtf(s2), EPSF);
    float2 o = {t0 * inv2, t1 * inv2};
    *(float2*)(out + (size_t)v * 112 + 96 + j0) = o;
}

extern "C" void kernel_launch(void* const* d_in, const int* in_sizes, int n_in,
                              void* d_out, int out_size, void* d_ws, size_t ws_size,
                              hipStream_t stream) {
    const int*   src  = (const int*)d_in[0];
    const int*   dst  = (const int*)d_in[1];
    const int*   ety  = (const int*)d_in[2];
    const float* ent  = (const float*)d_in[3];
    const float* entT = (const float*)d_in[4];
    const float* relE = (const float*)d_in[5];
    const float* relT = (const float*)d_in[6];
    const float* W1_0 = (const float*)d_in[7];
    const float* b1_0 = (const float*)d_in[8];
    const float* W2_0 = (const float*)d_in[9];
    const float* b2_0 = (const float*)d_in[10];
    const float* W1_1 = (const float*)d_in[11];
    const float* b1_1 = (const float*)d_in[12];
    const float* W2_1 = (const float*)d_in[13];
    const float* b2_1 = (const float*)d_in[14];
    float* out = (float*)d_out;

    const int E = in_sizes[0];
    const int N = in_sizes[3] / 64;
    const int nb = (N + 255) / 256;  // scan blocks (must be <= 1024)

    auto al256 = [](size_t x) { return (x + 255) & ~(size_t)255; };
    char* ws = (char*)d_ws;
    size_t offExatt = 0;
    size_t offS     = al256(offExatt + (size_t)E * 4);
    size_t offDot   = al256(offS + (size_t)N * 4);
    size_t offRow   = al256(offDot + (size_t)N * 4);
    size_t offSpk   = al256(offRow + (size_t)N * 4);
    size_t offPart  = al256(offSpk + (size_t)E * 4);
    size_t offN1    = al256(offPart + (size_t)nb * 4);
    float* exatt    = (float*)(ws + offExatt);
    float* sinv     = (float*)(ws + offS);
    float* dot      = (float*)(ws + offDot);
    int*   rowptr   = (int*)(ws + offRow);
    int*   spk      = (int*)(ws + offSpk);
    int*   part     = (int*)(ws + offPart);
    float* node1raw = (float*)(ws + offN1);   // [N,32]

    // ---- CSR build + per-node dot ----
    hipMemsetAsync(rowptr, 0, (size_t)N * 4, stream);
    precomp_dot<<<(N * 16 + 255) / 256, 256, 0, stream>>>(ent, entT, dot, N);
    int blkE = (E + 255) / 256;
    count_deg<<<blkE, 256, 0, stream>>>(dst, rowptr, E);
    scan_reduce<<<nb, 256, 0, stream>>>(rowptr, part, N);
    scan_part<<<1, 1024, 0, stream>>>(part, nb);
    scan_write<<<nb, 256, 0, stream>>>(rowptr, part, N);
    scatter_edges<<<blkE, 256, 0, stream>>>(src, dst, ety, rowptr, spk, E);

    // ---- fused layer 0: attention + softmax + message + node update ----
    fused_l0<<<(N + 15) / 16, 256, 0, stream>>>(
        rowptr, spk, ent, dot, relE, relT,
        W1_0, b1_0, W2_0, b2_0, exatt, sinv, node1raw, out, N);

    // ---- fused layer 1: message + node update + norms ----
    fused_l1<<<(N + 31) / 32, 256, 0, stream>>>(
        rowptr, spk, exatt, sinv, node1raw,
        W1_1, b1_1, W2_1, b2_1, out, N);
}

// Round 6
// 246.934 us; speedup vs baseline: 1.2865x; 1.1649x over previous
//
#include <hip/hip_runtime.h>
#include <math.h>

#define EPSF 1e-12f
#define LOG2E 1.44269504f

__device__ __forceinline__ float red16(float v) {
    v += __shfl_xor(v, 1, 16);
    v += __shfl_xor(v, 2, 16);
    v += __shfl_xor(v, 4, 16);
    v += __shfl_xor(v, 8, 16);
    return v;
}

__device__ __forceinline__ float red8(float v) {
    v += __shfl_xor(v, 1, 8);
    v += __shfl_xor(v, 2, 8);
    v += __shfl_xor(v, 4, 8);
    return v;
}

// tanh(x) = 1 - 2/(e^{2x}+1) with HW exp2/rcp (exact at +/-inf limits)
__device__ __forceinline__ float fast_tanh(float x) {
    float E = __builtin_amdgcn_exp2f(x * (2.0f * LOG2E));
    return 1.0f - 2.0f * __builtin_amdgcn_rcpf(E + 1.0f);
}

// 1/max(sqrt(x), 1e-12) == rsq(max(x, 1e-24)) (monotone transform, exact)
__device__ __forceinline__ float inv_norm(float x) {
    return __builtin_amdgcn_rsqf(fmaxf(x, 1e-24f));
}

__device__ __forceinline__ float leaky(float x) {
    return x > 0.0f ? x : 0.01f * x;
}

// ---------------- per-node dot precompute: dot[n] = ent[n] . entT[n] ----------
__global__ __launch_bounds__(256) void precomp_dot(
    const float* __restrict__ ent, const float* __restrict__ entT,
    float* __restrict__ dot, int N) {
    int gid = blockIdx.x * 256 + threadIdx.x;
    int v = gid >> 4, lane = gid & 15;
    if (v >= N) return;
    const float4 a = *(const float4*)(ent  + (size_t)v * 64 + lane * 4);
    const float4 b = *(const float4*)(entT + (size_t)v * 64 + lane * 4);
    float d = red16(a.x*b.x + a.y*b.y + a.z*b.z + a.w*b.w);
    if (lane == 0) dot[v] = d;
}

// ---------------- CSR build (counting sort by dst) ----------------

__global__ __launch_bounds__(256) void count_deg(
    const int* __restrict__ dst, int* __restrict__ deg, int E) {
    int e = blockIdx.x * 256 + threadIdx.x;
    if (e < E) atomicAdd(&deg[dst[e]], 1);
}

__global__ __launch_bounds__(256) void scan_reduce(
    const int* __restrict__ deg, int* __restrict__ part, int N) {
    __shared__ int sh[256];
    int t = threadIdx.x, i = blockIdx.x * 256 + t;
    sh[t] = (i < N) ? deg[i] : 0;
    __syncthreads();
    for (int off = 128; off > 0; off >>= 1) {
        if (t < off) sh[t] += sh[t + off];
        __syncthreads();
    }
    if (t == 0) part[blockIdx.x] = sh[0];
}

__global__ __launch_bounds__(1024) void scan_part(int* __restrict__ part, int nb) {
    __shared__ int sh[1024];
    int t = threadIdx.x;
    int x = (t < nb) ? part[t] : 0;
    sh[t] = x;
    __syncthreads();
    for (int off = 1; off < 1024; off <<= 1) {
        int y = (t >= off) ? sh[t - off] : 0;
        __syncthreads();
        sh[t] += y;
        __syncthreads();
    }
    if (t < nb) part[t] = sh[t] - x;  // exclusive
}

__global__ __launch_bounds__(256) void scan_write(
    int* __restrict__ rowptr, const int* __restrict__ part, int N) {
    __shared__ int sh[256];
    int t = threadIdx.x, i = blockIdx.x * 256 + t;
    int x = (i < N) ? rowptr[i] : 0;
    sh[t] = x;
    __syncthreads();
    for (int off = 1; off < 256; off <<= 1) {
        int y = (t >= off) ? sh[t - off] : 0;
        __syncthreads();
        sh[t] += y;
        __syncthreads();
    }
    if (i < N) rowptr[i] = part[blockIdx.x] + sh[t] - x;  // exclusive scan
}

// After this, rowptr[v] = end(v); start(v) = (v ? rowptr[v-1] : 0).
// Packs (src, etype) into one int per CSR slot: src | (ety << 20).
__global__ __launch_bounds__(256) void scatter_edges(
    const int* __restrict__ src, const int* __restrict__ dst,
    const int* __restrict__ ety, int* __restrict__ rowptr,
    int* __restrict__ spk, int E) {
    int e = blockIdx.x * 256 + threadIdx.x;
    if (e < E) {
        int slot = atomicAdd(&rowptr[dst[e]], 1);
        spk[slot] = src[e] | (ety[e] << 20);
    }
}

// ------------- fused layer-0: att + softmax + message + bi-layer GEMV -------
// 16 lanes per dst node. Edge loop processes TWO edges per iteration as
// independent interleaved pipelines (shared he/dh), with the next pair's
// te/dot gathers prefetched. Odd tail handled branch-free via zero weight.
__global__ __launch_bounds__(256) void fused_l0(
    const int* __restrict__ rowptr, const int* __restrict__ spk,
    const float* __restrict__ ent, const float* __restrict__ dot,
    const float* __restrict__ relE, const float* __restrict__ relT,
    const float* __restrict__ W1, const float* __restrict__ b1,
    const float* __restrict__ W2, const float* __restrict__ b2,
    float* __restrict__ exatt, float* __restrict__ sinv,
    float* __restrict__ node1raw, float* __restrict__ out, int N) {
    __shared__ float al[16][68];  // stride 68: 16B-aligned rows, bank offset 4
    __shared__ float bl[16][68];
    __shared__ float rT[16][68];  // rel tables staged in LDS (16 rels x 64)
    __shared__ float rE[16][68];
    int t = threadIdx.x;

    {   // stage rel tables: 256 threads = 16 rows x 16 quads
        int r = t >> 4, c = (t & 15) * 4;
        *(float4*)&rT[r][c] = *(const float4*)(relT + r * 64 + c);
        *(float4*)&rE[r][c] = *(const float4*)(relE + r * 64 + c);
    }
    __syncthreads();  // the only block barrier

    int nv = t >> 4, lane = t & 15;
    int v = blockIdx.x * 16 + nv;
    if (v >= N) return;

    int s = v ? rowptr[v - 1] : 0;
    int epos = rowptr[v];
    const float4 he = *(const float4*)(ent + (size_t)v * 64 + lane * 4);
    float dh = dot[v];

    float4 macc = {0.f, 0.f, 0.f, 0.f};
    float sumex = 0.0f;

    for (int base = s; base < epos; base += 16) {
        int rem = epos - base;
        int cnt = rem < 16 ? rem : 16;
        int mypk = spk[base + (lane < rem ? lane : rem - 1)];  // coalesced

        // prime pair 0 (pk1 duplicates pk0 when cnt==1; weight-zeroed below)
        int pk0 = __shfl(mypk, 0, 16);
        int pk1 = __shfl(mypk, cnt > 1 ? 1 : 0, 16);
        float4 te0 = *(const float4*)(ent + (size_t)(pk0 & 0xFFFFF) * 64 + lane * 4);
        float  sd0 = dot[pk0 & 0xFFFFF];
        float4 te1 = *(const float4*)(ent + (size_t)(pk1 & 0xFFFFF) * 64 + lane * 4);
        float  sd1 = dot[pk1 & 0xFFFFF];

        for (int k = 0; k < cnt; k += 2) {
            float4 ta = te0, tb = te1;
            float  sa = sd0, sb = sd1;
            int rva = (pk0 >> 20) & 15;
            int rvb = (pk1 >> 20) & 15;
            bool hasb = (k + 1) < cnt;

            if (k + 2 < cnt) {  // prefetch next pair while computing this one
                pk0 = __shfl(mypk, k + 2, 16);
                pk1 = __shfl(mypk, (k + 3 < cnt) ? (k + 3) : (k + 2), 16);
                te0 = *(const float4*)(ent + (size_t)(pk0 & 0xFFFFF) * 64 + lane * 4);
                sd0 = dot[pk0 & 0xFFFFF];
                te1 = *(const float4*)(ent + (size_t)(pk1 & 0xFFFFF) * 64 + lane * 4);
                sd1 = dot[pk1 & 0xFFFFF];
            }

            const float4 rpa = *(const float4*)&rT[rva][lane * 4];
            const float4 rea = *(const float4*)&rE[rva][lane * 4];
            const float4 rpb = *(const float4*)&rT[rvb][lane * 4];
            const float4 reb = *(const float4*)&rE[rvb][lane * 4];

            float4 mta, mha, mtb, mhb;
            mta.x = ta.x + sa * rpa.x; mta.y = ta.y + sa * rpa.y;
            mta.z = ta.z + sa * rpa.z; mta.w = ta.w + sa * rpa.w;
            mha.x = he.x + dh * rpa.x; mha.y = he.y + dh * rpa.y;
            mha.z = he.z + dh * rpa.z; mha.w = he.w + dh * rpa.w;
            mtb.x = tb.x + sb * rpb.x; mtb.y = tb.y + sb * rpb.y;
            mtb.z = tb.z + sb * rpb.z; mtb.w = tb.w + sb * rpb.w;
            mhb.x = he.x + dh * rpb.x; mhb.y = he.y + dh * rpb.y;
            mhb.z = he.z + dh * rpb.z; mhb.w = he.w + dh * rpb.w;

            float ssta = red16(mta.x*mta.x + mta.y*mta.y + mta.z*mta.z + mta.w*mta.w);
            float ssha = red16(mha.x*mha.x + mha.y*mha.y + mha.z*mha.z + mha.w*mha.w);
            float sstb = red16(mtb.x*mtb.x + mtb.y*mtb.y + mtb.z*mtb.z + mtb.w*mtb.w);
            float sshb = red16(mhb.x*mhb.x + mhb.y*mhb.y + mhb.z*mhb.z + mhb.w*mhb.w);
            float ita = inv_norm(ssta), iha = inv_norm(ssha);
            float itb = inv_norm(sstb), ihb = inv_norm(sshb);

            float txa = fast_tanh(mha.x * iha + rea.x);
            float tya = fast_tanh(mha.y * iha + rea.y);
            float tza = fast_tanh(mha.z * iha + rea.z);
            float twa = fast_tanh(mha.w * iha + rea.w);
            float txb = fast_tanh(mhb.x * ihb + reb.x);
            float tyb = fast_tanh(mhb.y * ihb + reb.y);
            float tzb = fast_tanh(mhb.z * ihb + reb.z);
            float twb = fast_tanh(mhb.w * ihb + reb.w);

            float atta = ita * red16(mta.x*txa + mta.y*tya + mta.z*tza + mta.w*twa);
            float attb = itb * red16(mtb.x*txb + mtb.y*tyb + mtb.z*tzb + mtb.w*twb);

            // softmax shift-invariant; |att| <= 8 so exp is safe without max-sub
            float exa  = __builtin_amdgcn_exp2f(atta * LOG2E);
            float exbR = __builtin_amdgcn_exp2f(attb * LOG2E);
            float exb  = hasb ? exbR : 0.0f;

            if (lane == 0) {
                exatt[base + k] = exa;              // raw; consumers scale by sinv
                if (hasb) exatt[base + k + 1] = exbR;
            }
            sumex += exa + exb;
            macc.x += exa * ta.x + exb * tb.x;
            macc.y += exa * ta.y + exb * tb.y;
            macc.z += exa * ta.z + exb * tb.z;
            macc.w += exa * ta.w + exb * tb.w;
        }
    }

    float inv = 1.0f / fmaxf(sumex, EPSF);
    if (lane == 0) sinv[v] = inv;
    macc.x *= inv; macc.y *= inv; macc.z *= inv; macc.w *= inv;

    // out cols 0..63 = ent_embed
    *(float4*)(out + (size_t)v * 112 + lane * 4) = he;

    float4 av, bv;
    av.x = he.x + macc.x; av.y = he.y + macc.y;
    av.z = he.z + macc.z; av.w = he.w + macc.w;
    bv.x = he.x * macc.x; bv.y = he.y * macc.y;
    bv.z = he.z * macc.z; bv.w = he.w * macc.w;
    *(float4*)&al[nv][lane * 4] = av;
    *(float4*)&bl[nv][lane * 4] = bv;
    // no __syncthreads: same 16 lanes (same wave) read these rows below

    #pragma unroll
    for (int jo = 0; jo < 2; ++jo) {
        int j = lane + jo * 16;
        float acc1 = b1[j], acc2 = b2[j];
        #pragma unroll
        for (int d = 0; d < 64; d += 4) {
            float4 a4 = *(const float4*)&al[nv][d];
            float4 b4 = *(const float4*)&bl[nv][d];
            acc1 += a4.x * W1[(d+0)*32 + j] + a4.y * W1[(d+1)*32 + j]
                  + a4.z * W1[(d+2)*32 + j] + a4.w * W1[(d+3)*32 + j];
            acc2 += b4.x * W2[(d+0)*32 + j] + b4.y * W2[(d+1)*32 + j]
                  + b4.z * W2[(d+2)*32 + j] + b4.w * W2[(d+3)*32 + j];
        }
        node1raw[(size_t)v * 32 + j] = leaky(acc1) + leaky(acc2);
    }
}

// ------------- fused layer-1: message gather + bi-layer GEMV + norms --------
// 8 lanes per node (32 nodes / block). Dual-edge pipeline; no block barrier.
__global__ __launch_bounds__(256) void fused_l1(
    const int* __restrict__ rowptr, const int* __restrict__ spk,
    const float* __restrict__ exatt, const float* __restrict__ sinv,
    const float* __restrict__ node1raw,
    const float* __restrict__ W1, const float* __restrict__ b1,
    const float* __restrict__ W2, const float* __restrict__ b2,
    float* __restrict__ out, int N) {
    __shared__ float A[32][36];  // stride 36: 16B-aligned rows, bank offset 4
    __shared__ float B[32][36];
    int t = threadIdx.x;
    int nv = t >> 3, lane = t & 7;
    int v = blockIdx.x * 32 + nv;
    if (v >= N) return;

    int s = v ? rowptr[v - 1] : 0;
    int epos = rowptr[v];
    float4 n = *(const float4*)(node1raw + (size_t)v * 32 + lane * 4);
    float4 acc = {0.f, 0.f, 0.f, 0.f};

    for (int base = s; base < epos; base += 8) {
        int rem = epos - base;
        int cnt = rem < 8 ? rem : 8;
        int idx = base + (lane < rem ? lane : rem - 1);
        int   mypk = spk[idx];
        float myex = exatt[idx];

        int pk0 = __shfl(mypk, 0, 8);
        int pk1 = __shfl(mypk, cnt > 1 ? 1 : 0, 8);
        float4 x0 = *(const float4*)(node1raw + (size_t)(pk0 & 0xFFFFF) * 32 + lane * 4);
        float4 x1 = *(const float4*)(node1raw + (size_t)(pk1 & 0xFFFFF) * 32 + lane * 4);

        for (int k = 0; k < cnt; k += 2) {
            float4 xa = x0, xb = x1;
            float aa = __shfl(myex, k, 8);
            float ab = __shfl(myex, (k + 1 < cnt) ? (k + 1) : k, 8);
            if (!((k + 1) < cnt)) ab = 0.0f;

            if (k + 2 < cnt) {
                pk0 = __shfl(mypk, k + 2, 8);
                pk1 = __shfl(mypk, (k + 3 < cnt) ? (k + 3) : (k + 2), 8);
                x0 = *(const float4*)(node1raw + (size_t)(pk0 & 0xFFFFF) * 32 + lane * 4);
                x1 = *(const float4*)(node1raw + (size_t)(pk1 & 0xFFFFF) * 32 + lane * 4);
            }
            acc.x += aa * xa.x + ab * xb.x;
            acc.y += aa * xa.y + ab * xb.y;
            acc.z += aa * xa.z + ab * xb.z;
            acc.w += aa * xa.w + ab * xb.w;
        }
    }
    float inv = sinv[v];
    acc.x *= inv; acc.y *= inv; acc.z *= inv; acc.w *= inv;

    // normalized node1 -> out cols 64..95
    float ss = red8(n.x*n.x + n.y*n.y + n.z*n.z + n.w*n.w);
    float inv1 = inv_norm(ss);
    float4 nn = {n.x*inv1, n.y*inv1, n.z*inv1, n.w*inv1};
    *(float4*)(out + (size_t)v * 112 + 64 + lane * 4) = nn;

    float4 av = {n.x + acc.x, n.y + acc.y, n.z + acc.z, n.w + acc.w};
    float4 bv = {n.x * acc.x, n.y * acc.y, n.z * acc.z, n.w * acc.w};
    *(float4*)&A[nv][lane * 4] = av;
    *(float4*)&B[nv][lane * 4] = bv;
    // no __syncthreads: same 8 lanes (same wave) read these rows below

    int j0 = lane * 2;
    float a10 = b1[j0], a11 = b1[j0 + 1];
    float a20 = b2[j0], a21 = b2[j0 + 1];
    #pragma unroll
    for (int d = 0; d < 32; d += 4) {
        float4 a4 = *(const float4*)&A[nv][d];
        float4 b4 = *(const float4*)&B[nv][d];
        float2 w0 = *(const float2*)(W1 + (d+0)*16 + j0);
        float2 w1 = *(const float2*)(W1 + (d+1)*16 + j0);
        float2 w2 = *(const float2*)(W1 + (d+2)*16 + j0);
        float2 w3 = *(const float2*)(W1 + (d+3)*16 + j0);
        a10 += a4.x*w0.x + a4.y*w1.x + a4.z*w2.x + a4.w*w3.x;
        a11 += a4.x*w0.y + a4.y*w1.y + a4.z*w2.y + a4.w*w3.y;
        float2 u0 = *(const float2*)(W2 + (d+0)*16 + j0);
        float2 u1 = *(const float2*)(W2 + (d+1)*16 + j0);
        float2 u2 = *(const float2*)(W2 + (d+2)*16 + j0);
        float2 u3 = *(const float2*)(W2 + (d+3)*16 + j0);
        a20 += b4.x*u0.x + b4.y*u1.x + b4.z*u2.x + b4.w*u3.x;
        a21 += b4.x*u0.y + b4.y*u1.y + b4.z*u2.y + b4.w*u3.y;
    }
    float t0 = leaky(a10) + leaky(a20);
    float t1 = leaky(a11) + leaky(a21);
    float s2 = red8(t0*t0 + t1*t1);
    float inv2 = inv_norm(s2);
    float2 o = {t0 * inv2, t1 * inv2};
    *(float2*)(out + (size_t)v * 112 + 96 + j0) = o;
}

extern "C" void kernel_launch(void* const* d_in, const int* in_sizes, int n_in,
                              void* d_out, int out_size, void* d_ws, size_t ws_size,
                              hipStream_t stream) {
    const int*   src  = (const int*)d_in[0];
    const int*   dst  = (const int*)d_in[1];
    const int*   ety  = (const int*)d_in[2];
    const float* ent  = (const float*)d_in[3];
    const float* entT = (const float*)d_in[4];
    const float* relE = (const float*)d_in[5];
    const float* relT = (const float*)d_in[6];
    const float* W1_0 = (const float*)d_in[7];
    const float* b1_0 = (const float*)d_in[8];
    const float* W2_0 = (const float*)d_in[9];
    const float* b2_0 = (const float*)d_in[10];
    const float* W1_1 = (const float*)d_in[11];
    const float* b1_1 = (const float*)d_in[12];
    const float* W2_1 = (const float*)d_in[13];
    const float* b2_1 = (const float*)d_in[14];
    float* out = (float*)d_out;

    const int E = in_sizes[0];
    const int N = in_sizes[3] / 64;
    const int nb = (N + 255) / 256;  // scan blocks (must be <= 1024)

    auto al256 = [](size_t x) { return (x + 255) & ~(size_t)255; };
    char* ws = (char*)d_ws;
    size_t offExatt = 0;
    size_t offS     = al256(offExatt + (size_t)E * 4);
    size_t offDot   = al256(offS + (size_t)N * 4);
    size_t offRow   = al256(offDot + (size_t)N * 4);
    size_t offSpk   = al256(offRow + (size_t)N * 4);
    size_t offPart  = al256(offSpk + (size_t)E * 4);
    size_t offN1    = al256(offPart + (size_t)nb * 4);
    float* exatt    = (float*)(ws + offExatt);
    float* sinv     = (float*)(ws + offS);
    float* dot      = (float*)(ws + offDot);
    int*   rowptr   = (int*)(ws + offRow);
    int*   spk      = (int*)(ws + offSpk);
    int*   part     = (int*)(ws + offPart);
    float* node1raw = (float*)(ws + offN1);   // [N,32]

    // ---- CSR build + per-node dot ----
    hipMemsetAsync(rowptr, 0, (size_t)N * 4, stream);
    precomp_dot<<<(N * 16 + 255) / 256, 256, 0, stream>>>(ent, entT, dot, N);
    int blkE = (E + 255) / 256;
    count_deg<<<blkE, 256, 0, stream>>>(dst, rowptr, E);
    scan_reduce<<<nb, 256, 0, stream>>>(rowptr, part, N);
    scan_part<<<1, 1024, 0, stream>>>(part, nb);
    scan_write<<<nb, 256, 0, stream>>>(rowptr, part, N);
    scatter_edges<<<blkE, 256, 0, stream>>>(src, dst, ety, rowptr, spk, E);

    // ---- fused layer 0: attention + softmax + message + node update ----
    fused_l0<<<(N + 15) / 16, 256, 0, stream>>>(
        rowptr, spk, ent, dot, relE, relT,
        W1_0, b1_0, W2_0, b2_0, exatt, sinv, node1raw, out, N);

    // ---- fused layer 1: message + node update + norms ----
    fused_l1<<<(N + 31) / 32, 256, 0, stream>>>(
        rowptr, spk, exatt, sinv, node1raw,
        W1_1, b1_1, W2_1, b2_1, out, N);
}

// Round 7
// 230.987 us; speedup vs baseline: 1.3753x; 1.0690x over previous
//
#include <hip/hip_runtime.h>
#include <math.h>

#define EPSF 1e-12f
#define LOG2E 1.44269504f

__device__ __forceinline__ float red16(float v) {
    v += __shfl_xor(v, 1, 16);
    v += __shfl_xor(v, 2, 16);
    v += __shfl_xor(v, 4, 16);
    v += __shfl_xor(v, 8, 16);
    return v;
}

__device__ __forceinline__ float red8(float v) {
    v += __shfl_xor(v, 1, 8);
    v += __shfl_xor(v, 2, 8);
    v += __shfl_xor(v, 4, 8);
    return v;
}

// tanh(x) = 1 - 2/(e^{2x}+1) with HW exp2/rcp (exact at +/-inf limits)
__device__ __forceinline__ float fast_tanh(float x) {
    float E = __builtin_amdgcn_exp2f(x * (2.0f * LOG2E));
    return 1.0f - 2.0f * __builtin_amdgcn_rcpf(E + 1.0f);
}

// 1/max(sqrt(x), 1e-12) == rsq(max(x, 1e-24)) (monotone transform, exact)
__device__ __forceinline__ float inv_norm(float x) {
    return __builtin_amdgcn_rsqf(fmaxf(x, 1e-24f));
}

__device__ __forceinline__ float leaky(float x) {
    return x > 0.0f ? x : 0.01f * x;
}

// ---- prep: per-node dot (first N*16 threads) + degree count (next E) ----
__global__ __launch_bounds__(256) void prep(
    const float* __restrict__ ent, const float* __restrict__ entT,
    float* __restrict__ dot, const int* __restrict__ dst,
    int* __restrict__ deg, int N16, int E) {
    int gid = blockIdx.x * 256 + threadIdx.x;
    if (gid < N16) {   // N16 is a multiple of 16, groups never straddle
        int v = gid >> 4, lane = gid & 15;
        const float4 a = *(const float4*)(ent  + (size_t)v * 64 + lane * 4);
        const float4 b = *(const float4*)(entT + (size_t)v * 64 + lane * 4);
        float d = red16(a.x*b.x + a.y*b.y + a.z*b.z + a.w*b.w);
        if (lane == 0) dot[v] = d;
    } else {
        int e = gid - N16;
        if (e < E) atomicAdd(&deg[dst[e]], 1);
    }
}

// ---------------- CSR scan kernels ----------------

__global__ __launch_bounds__(256) void scan_reduce(
    const int* __restrict__ deg, int* __restrict__ part, int N) {
    __shared__ int sh[256];
    int t = threadIdx.x, i = blockIdx.x * 256 + t;
    sh[t] = (i < N) ? deg[i] : 0;
    __syncthreads();
    for (int off = 128; off > 0; off >>= 1) {
        if (t < off) sh[t] += sh[t + off];
        __syncthreads();
    }
    if (t == 0) part[blockIdx.x] = sh[0];
}

__global__ __launch_bounds__(1024) void scan_part(int* __restrict__ part, int nb) {
    __shared__ int sh[1024];
    int t = threadIdx.x;
    int x = (t < nb) ? part[t] : 0;
    sh[t] = x;
    __syncthreads();
    for (int off = 1; off < 1024; off <<= 1) {
        int y = (t >= off) ? sh[t - off] : 0;
        __syncthreads();
        sh[t] += y;
        __syncthreads();
    }
    if (t < nb) part[t] = sh[t] - x;  // exclusive
}

__global__ __launch_bounds__(256) void scan_write(
    int* __restrict__ rowptr, const int* __restrict__ part, int N) {
    __shared__ int sh[256];
    int t = threadIdx.x, i = blockIdx.x * 256 + t;
    int x = (i < N) ? rowptr[i] : 0;
    sh[t] = x;
    __syncthreads();
    for (int off = 1; off < 256; off <<= 1) {
        int y = (t >= off) ? sh[t - off] : 0;
        __syncthreads();
        sh[t] += y;
        __syncthreads();
    }
    if (i < N) rowptr[i] = part[blockIdx.x] + sh[t] - x;  // exclusive scan
}

// After this, rowptr[v] = end(v); start(v) = (v ? rowptr[v-1] : 0).
// Packs (src, etype) into one int per CSR slot: src | (ety << 20).
__global__ __launch_bounds__(256) void scatter_edges(
    const int* __restrict__ src, const int* __restrict__ dst,
    const int* __restrict__ ety, int* __restrict__ rowptr,
    int* __restrict__ spk, int E) {
    int e = blockIdx.x * 256 + threadIdx.x;
    if (e < E) {
        int slot = atomicAdd(&rowptr[dst[e]], 1);
        spk[slot] = src[e] | (ety[e] << 20);
    }
}

// ------------- fused layer-0: att + softmax + message + bi-layer GEMV -------
// 32 lanes per dst node (8 nodes / 256-thread block): two 16-lane halves each
// walk half the node's edge list with a dual-edge pipeline + next-pair
// prefetch; halves combined via width-32 shfl_xor. GEMV: 32 lanes x 1 col.
__global__ __launch_bounds__(256) void fused_l0(
    const int* __restrict__ rowptr, const int* __restrict__ spk,
    const float* __restrict__ ent, const float* __restrict__ dot,
    const float* __restrict__ relE, const float* __restrict__ relT,
    const float* __restrict__ W1, const float* __restrict__ b1,
    const float* __restrict__ W2, const float* __restrict__ b2,
    float* __restrict__ exatt, float* __restrict__ sinv,
    float* __restrict__ node1raw, float* __restrict__ out, int N) {
    __shared__ float al[8][68];   // stride 68: 16B-aligned rows, bank offset 4
    __shared__ float bl[8][68];
    __shared__ float rT[16][68];  // rel tables staged in LDS (16 rels x 64)
    __shared__ float rE[16][68];
    int t = threadIdx.x;

    {   // stage rel tables: 256 threads = 16 rows x 16 quads
        int r = t >> 4, c = (t & 15) * 4;
        *(float4*)&rT[r][c] = *(const float4*)(relT + r * 64 + c);
        *(float4*)&rE[r][c] = *(const float4*)(relE + r * 64 + c);
    }
    __syncthreads();  // the only block barrier

    int nv = t >> 5, half = (t >> 4) & 1, lane = t & 15;
    int v = blockIdx.x * 8 + nv;
    if (v >= N) return;

    int s = v ? rowptr[v - 1] : 0;
    int epos = rowptr[v];
    int deg = epos - s;
    int mid = s + ((deg + 1) >> 1);
    int hs   = half ? mid  : s;
    int hend = half ? epos : mid;

    const float4 he = *(const float4*)(ent + (size_t)v * 64 + lane * 4);
    float dh = dot[v];

    float4 macc = {0.f, 0.f, 0.f, 0.f};
    float sumex = 0.0f;

    for (int base = hs; base < hend; base += 16) {
        int rem = hend - base;
        int cnt = rem < 16 ? rem : 16;
        int mypk = spk[base + (lane < rem ? lane : rem - 1)];  // coalesced

        // prime pair 0 (pk1 duplicates pk0 when cnt==1; weight-zeroed below)
        int pk0 = __shfl(mypk, 0, 16);
        int pk1 = __shfl(mypk, cnt > 1 ? 1 : 0, 16);
        float4 te0 = *(const float4*)(ent + (size_t)(pk0 & 0xFFFFF) * 64 + lane * 4);
        float  sd0 = dot[pk0 & 0xFFFFF];
        float4 te1 = *(const float4*)(ent + (size_t)(pk1 & 0xFFFFF) * 64 + lane * 4);
        float  sd1 = dot[pk1 & 0xFFFFF];

        for (int k = 0; k < cnt; k += 2) {
            float4 ta = te0, tb = te1;
            float  sa = sd0, sb = sd1;
            int rva = (pk0 >> 20) & 15;
            int rvb = (pk1 >> 20) & 15;
            bool hasb = (k + 1) < cnt;

            if (k + 2 < cnt) {  // prefetch next pair while computing this one
                pk0 = __shfl(mypk, k + 2, 16);
                pk1 = __shfl(mypk, (k + 3 < cnt) ? (k + 3) : (k + 2), 16);
                te0 = *(const float4*)(ent + (size_t)(pk0 & 0xFFFFF) * 64 + lane * 4);
                sd0 = dot[pk0 & 0xFFFFF];
                te1 = *(const float4*)(ent + (size_t)(pk1 & 0xFFFFF) * 64 + lane * 4);
                sd1 = dot[pk1 & 0xFFFFF];
            }

            const float4 rpa = *(const float4*)&rT[rva][lane * 4];
            const float4 rea = *(const float4*)&rE[rva][lane * 4];
            const float4 rpb = *(const float4*)&rT[rvb][lane * 4];
            const float4 reb = *(const float4*)&rE[rvb][lane * 4];

            float4 mta, mha, mtb, mhb;
            mta.x = ta.x + sa * rpa.x; mta.y = ta.y + sa * rpa.y;
            mta.z = ta.z + sa * rpa.z; mta.w = ta.w + sa * rpa.w;
            mha.x = he.x + dh * rpa.x; mha.y = he.y + dh * rpa.y;
            mha.z = he.z + dh * rpa.z; mha.w = he.w + dh * rpa.w;
            mtb.x = tb.x + sb * rpb.x; mtb.y = tb.y + sb * rpb.y;
            mtb.z = tb.z + sb * rpb.z; mtb.w = tb.w + sb * rpb.w;
            mhb.x = he.x + dh * rpb.x; mhb.y = he.y + dh * rpb.y;
            mhb.z = he.z + dh * rpb.z; mhb.w = he.w + dh * rpb.w;

            float ssta = red16(mta.x*mta.x + mta.y*mta.y + mta.z*mta.z + mta.w*mta.w);
            float ssha = red16(mha.x*mha.x + mha.y*mha.y + mha.z*mha.z + mha.w*mha.w);
            float sstb = red16(mtb.x*mtb.x + mtb.y*mtb.y + mtb.z*mtb.z + mtb.w*mtb.w);
            float sshb = red16(mhb.x*mhb.x + mhb.y*mhb.y + mhb.z*mhb.z + mhb.w*mhb.w);
            float ita = inv_norm(ssta), iha = inv_norm(ssha);
            float itb = inv_norm(sstb), ihb = inv_norm(sshb);

            float txa = fast_tanh(mha.x * iha + rea.x);
            float tya = fast_tanh(mha.y * iha + rea.y);
            float tza = fast_tanh(mha.z * iha + rea.z);
            float twa = fast_tanh(mha.w * iha + rea.w);
            float txb = fast_tanh(mhb.x * ihb + reb.x);
            float tyb = fast_tanh(mhb.y * ihb + reb.y);
            float tzb = fast_tanh(mhb.z * ihb + reb.z);
            float twb = fast_tanh(mhb.w * ihb + reb.w);

            float atta = ita * red16(mta.x*txa + mta.y*tya + mta.z*tza + mta.w*twa);
            float attb = itb * red16(mtb.x*txb + mtb.y*tyb + mtb.z*tzb + mtb.w*twb);

            // softmax shift-invariant; |att| <= 8 so exp is safe without max-sub
            float exa  = __builtin_amdgcn_exp2f(atta * LOG2E);
            float exbR = __builtin_amdgcn_exp2f(attb * LOG2E);
            float exb  = hasb ? exbR : 0.0f;

            if (lane == 0) {
                exatt[base + k] = exa;              // raw; consumers scale by sinv
                if (hasb) exatt[base + k + 1] = exbR;
            }
            sumex += exa + exb;
            macc.x += exa * ta.x + exb * tb.x;
            macc.y += exa * ta.y + exb * tb.y;
            macc.z += exa * ta.z + exb * tb.z;
            macc.w += exa * ta.w + exb * tb.w;
        }
    }

    // combine the two halves of this node (width-32 xor-by-16)
    sumex  += __shfl_xor(sumex,  16, 32);
    macc.x += __shfl_xor(macc.x, 16, 32);
    macc.y += __shfl_xor(macc.y, 16, 32);
    macc.z += __shfl_xor(macc.z, 16, 32);
    macc.w += __shfl_xor(macc.w, 16, 32);

    float inv = 1.0f / fmaxf(sumex, EPSF);
    if ((t & 31) == 0) sinv[v] = inv;
    macc.x *= inv; macc.y *= inv; macc.z *= inv; macc.w *= inv;

    if (!half) {
        // out cols 0..63 = ent_embed
        *(float4*)(out + (size_t)v * 112 + lane * 4) = he;
        float4 av, bv;
        av.x = he.x + macc.x; av.y = he.y + macc.y;
        av.z = he.z + macc.z; av.w = he.w + macc.w;
        bv.x = he.x * macc.x; bv.y = he.y * macc.y;
        bv.z = he.z * macc.z; bv.w = he.w * macc.w;
        *(float4*)&al[nv][lane * 4] = av;
        *(float4*)&bl[nv][lane * 4] = bv;
    }
    // no __syncthreads: writers and readers are the same wave (program order)

    int j = t & 31;
    float acc1 = b1[j], acc2 = b2[j];
    #pragma unroll
    for (int d = 0; d < 64; d += 4) {
        float4 a4 = *(const float4*)&al[nv][d];
        float4 b4 = *(const float4*)&bl[nv][d];
        acc1 += a4.x * W1[(d+0)*32 + j] + a4.y * W1[(d+1)*32 + j]
              + a4.z * W1[(d+2)*32 + j] + a4.w * W1[(d+3)*32 + j];
        acc2 += b4.x * W2[(d+0)*32 + j] + b4.y * W2[(d+1)*32 + j]
              + b4.z * W2[(d+2)*32 + j] + b4.w * W2[(d+3)*32 + j];
    }
    node1raw[(size_t)v * 32 + j] = leaky(acc1) + leaky(acc2);
}

// ------------- fused layer-1: message gather + bi-layer GEMV + norms --------
// 16 lanes per node (16 nodes / block): two 8-lane halves, dual-edge pipeline.
__global__ __launch_bounds__(256) void fused_l1(
    const int* __restrict__ rowptr, const int* __restrict__ spk,
    const float* __restrict__ exatt, const float* __restrict__ sinv,
    const float* __restrict__ node1raw,
    const float* __restrict__ W1, const float* __restrict__ b1,
    const float* __restrict__ W2, const float* __restrict__ b2,
    float* __restrict__ out, int N) {
    __shared__ float A[16][36];  // stride 36: 16B-aligned rows, bank offset 4
    __shared__ float B[16][36];
    int t = threadIdx.x;
    int nv = t >> 4, half = (t >> 3) & 1, lane = t & 7;
    int v = blockIdx.x * 16 + nv;
    if (v >= N) return;

    int s = v ? rowptr[v - 1] : 0;
    int epos = rowptr[v];
    int deg = epos - s;
    int mid = s + ((deg + 1) >> 1);
    int hs   = half ? mid  : s;
    int hend = half ? epos : mid;

    float4 n = *(const float4*)(node1raw + (size_t)v * 32 + lane * 4);
    float4 acc = {0.f, 0.f, 0.f, 0.f};

    for (int base = hs; base < hend; base += 8) {
        int rem = hend - base;
        int cnt = rem < 8 ? rem : 8;
        int idx = base + (lane < rem ? lane : rem - 1);
        int   mypk = spk[idx];
        float myex = exatt[idx];

        int pk0 = __shfl(mypk, 0, 8);
        int pk1 = __shfl(mypk, cnt > 1 ? 1 : 0, 8);
        float4 x0 = *(const float4*)(node1raw + (size_t)(pk0 & 0xFFFFF) * 32 + lane * 4);
        float4 x1 = *(const float4*)(node1raw + (size_t)(pk1 & 0xFFFFF) * 32 + lane * 4);

        for (int k = 0; k < cnt; k += 2) {
            float4 xa = x0, xb = x1;
            float aa = __shfl(myex, k, 8);
            float ab = __shfl(myex, (k + 1 < cnt) ? (k + 1) : k, 8);
            if (!((k + 1) < cnt)) ab = 0.0f;

            if (k + 2 < cnt) {
                pk0 = __shfl(mypk, k + 2, 8);
                pk1 = __shfl(mypk, (k + 3 < cnt) ? (k + 3) : (k + 2), 8);
                x0 = *(const float4*)(node1raw + (size_t)(pk0 & 0xFFFFF) * 32 + lane * 4);
                x1 = *(const float4*)(node1raw + (size_t)(pk1 & 0xFFFFF) * 32 + lane * 4);
            }
            acc.x += aa * xa.x + ab * xb.x;
            acc.y += aa * xa.y + ab * xb.y;
            acc.z += aa * xa.z + ab * xb.z;
            acc.w += aa * xa.w + ab * xb.w;
        }
    }
    // combine halves (width-16 xor-by-8)
    acc.x += __shfl_xor(acc.x, 8, 16);
    acc.y += __shfl_xor(acc.y, 8, 16);
    acc.z += __shfl_xor(acc.z, 8, 16);
    acc.w += __shfl_xor(acc.w, 8, 16);

    float inv = sinv[v];
    acc.x *= inv; acc.y *= inv; acc.z *= inv; acc.w *= inv;

    float ss = red8(n.x*n.x + n.y*n.y + n.z*n.z + n.w*n.w);
    float inv1 = inv_norm(ss);

    if (!half) {
        float4 nn = {n.x*inv1, n.y*inv1, n.z*inv1, n.w*inv1};
        *(float4*)(out + (size_t)v * 112 + 64 + lane * 4) = nn;
        float4 av = {n.x + acc.x, n.y + acc.y, n.z + acc.z, n.w + acc.w};
        float4 bv = {n.x * acc.x, n.y * acc.y, n.z * acc.z, n.w * acc.w};
        *(float4*)&A[nv][lane * 4] = av;
        *(float4*)&B[nv][lane * 4] = bv;
    }
    // no __syncthreads: writers and readers are the same wave (program order)

    int j = t & 15;
    float a1 = b1[j], a2 = b2[j];
    #pragma unroll
    for (int d = 0; d < 32; d += 4) {
        float4 a4 = *(const float4*)&A[nv][d];
        float4 b4 = *(const float4*)&B[nv][d];
        a1 += a4.x * W1[(d+0)*16 + j] + a4.y * W1[(d+1)*16 + j]
            + a4.z * W1[(d+2)*16 + j] + a4.w * W1[(d+3)*16 + j];
        a2 += b4.x * W2[(d+0)*16 + j] + b4.y * W2[(d+1)*16 + j]
            + b4.z * W2[(d+2)*16 + j] + b4.w * W2[(d+3)*16 + j];
    }
    float tot = leaky(a1) + leaky(a2);
    float s2 = red16(tot * tot);
    float inv2 = inv_norm(s2);
    out[(size_t)v * 112 + 96 + j] = tot * inv2;  // cols 96..111
}

extern "C" void kernel_launch(void* const* d_in, const int* in_sizes, int n_in,
                              void* d_out, int out_size, void* d_ws, size_t ws_size,
                              hipStream_t stream) {
    const int*   src  = (const int*)d_in[0];
    const int*   dst  = (const int*)d_in[1];
    const int*   ety  = (const int*)d_in[2];
    const float* ent  = (const float*)d_in[3];
    const float* entT = (const float*)d_in[4];
    const float* relE = (const float*)d_in[5];
    const float* relT = (const float*)d_in[6];
    const float* W1_0 = (const float*)d_in[7];
    const float* b1_0 = (const float*)d_in[8];
    const float* W2_0 = (const float*)d_in[9];
    const float* b2_0 = (const float*)d_in[10];
    const float* W1_1 = (const float*)d_in[11];
    const float* b1_1 = (const float*)d_in[12];
    const float* W2_1 = (const float*)d_in[13];
    const float* b2_1 = (const float*)d_in[14];
    float* out = (float*)d_out;

    const int E = in_sizes[0];
    const int N = in_sizes[3] / 64;
    const int nb = (N + 255) / 256;  // scan blocks (must be <= 1024)

    auto al256 = [](size_t x) { return (x + 255) & ~(size_t)255; };
    char* ws = (char*)d_ws;
    size_t offExatt = 0;
    size_t offS     = al256(offExatt + (size_t)E * 4);
    size_t offDot   = al256(offS + (size_t)N * 4);
    size_t offRow   = al256(offDot + (size_t)N * 4);
    size_t offSpk   = al256(offRow + (size_t)N * 4);
    size_t offPart  = al256(offSpk + (size_t)E * 4);
    size_t offN1    = al256(offPart + (size_t)nb * 4);
    float* exatt    = (float*)(ws + offExatt);
    float* sinv     = (float*)(ws + offS);
    float* dot      = (float*)(ws + offDot);
    int*   rowptr   = (int*)(ws + offRow);
    int*   spk      = (int*)(ws + offSpk);
    int*   part     = (int*)(ws + offPart);
    float* node1raw = (float*)(ws + offN1);   // [N,32]

    // ---- CSR build + per-node dot ----
    hipMemsetAsync(rowptr, 0, (size_t)N * 4, stream);
    int N16 = N * 16;
    prep<<<(N16 + E + 255) / 256, 256, 0, stream>>>(ent, entT, dot, dst,
                                                    rowptr, N16, E);
    scan_reduce<<<nb, 256, 0, stream>>>(rowptr, part, N);
    scan_part<<<1, 1024, 0, stream>>>(part, nb);
    scan_write<<<nb, 256, 0, stream>>>(rowptr, part, N);
    int blkE = (E + 255) / 256;
    scatter_edges<<<blkE, 256, 0, stream>>>(src, dst, ety, rowptr, spk, E);

    // ---- fused layer 0: attention + softmax + message + node update ----
    fused_l0<<<(N + 7) / 8, 256, 0, stream>>>(
        rowptr, spk, ent, dot, relE, relT,
        W1_0, b1_0, W2_0, b2_0, exatt, sinv, node1raw, out, N);

    // ---- fused layer 1: message + node update + norms ----
    fused_l1<<<(N + 15) / 16, 256, 0, stream>>>(
        rowptr, spk, exatt, sinv, node1raw,
        W1_1, b1_1, W2_1, b2_1, out, N);
}

// Round 8
// 210.271 us; speedup vs baseline: 1.5108x; 1.0985x over previous
//
#include <hip/hip_runtime.h>
#include <math.h>

#define EPSF 1e-12f
#define LOG2E 1.44269504f

// ---- DPP-based reductions (no DS pipe, no lane-addr calc) ----
// ctrl: 0xB1 quad_perm[1,0,3,2]=xor1, 0x4E quad_perm[2,3,0,1]=xor2,
//       0x141 row_half_mirror (^7 in 8), 0x140 row_mirror (^15 in 16),
//       0x128 row_ror:8 (pairs lane i with (i+8)%16 == i^8 within 16).
template <int CTRL>
__device__ __forceinline__ float dppadd(float x) {
    union { float f; int i; } u, r;
    u.f = x;
    r.i = __builtin_amdgcn_update_dpp(0, u.i, CTRL, 0xF, 0xF, false);
    return x + r.f;
}
__device__ __forceinline__ float red16(float v) {
    v = dppadd<0xB1>(v); v = dppadd<0x4E>(v);
    v = dppadd<0x141>(v); v = dppadd<0x140>(v);
    return v;  // all 16 lanes hold the total
}
__device__ __forceinline__ float red8(float v) {
    v = dppadd<0xB1>(v); v = dppadd<0x4E>(v); v = dppadd<0x141>(v);
    return v;  // all 8 lanes hold the total
}
__device__ __forceinline__ float xor8add(float v) {  // combine 8-halves in 16
    return dppadd<0x128>(v);
}

// tanh(x) = 1 - 2/(e^{2x}+1) with HW exp2/rcp (exact at +/-inf limits)
__device__ __forceinline__ float fast_tanh(float x) {
    float E = __builtin_amdgcn_exp2f(x * (2.0f * LOG2E));
    return 1.0f - 2.0f * __builtin_amdgcn_rcpf(E + 1.0f);
}

// 1/max(sqrt(x), 1e-12) == rsq(max(x, 1e-24)) (monotone transform, exact)
__device__ __forceinline__ float inv_norm(float x) {
    return __builtin_amdgcn_rsqf(fmaxf(x, 1e-24f));
}

__device__ __forceinline__ float leaky(float x) {
    return x > 0.0f ? x : 0.01f * x;
}

// ---- prep: per-node dot (first N*16 threads) + degree count (next E) ----
__global__ __launch_bounds__(256) void prep(
    const float* __restrict__ ent, const float* __restrict__ entT,
    float* __restrict__ dot, const int* __restrict__ dst,
    int* __restrict__ deg, int N16, int E) {
    int gid = blockIdx.x * 256 + threadIdx.x;
    if (gid < N16) {   // N16 is a multiple of 16, 16-lane rows never straddle
        int v = gid >> 4, lane = gid & 15;
        const float4 a = *(const float4*)(ent  + (size_t)v * 64 + lane * 4);
        const float4 b = *(const float4*)(entT + (size_t)v * 64 + lane * 4);
        float d = red16(a.x*b.x + a.y*b.y + a.z*b.z + a.w*b.w);
        if (lane == 0) dot[v] = d;
    } else {
        int e = gid - N16;
        if (e < E) atomicAdd(&deg[dst[e]], 1);
    }
}

// ---------------- CSR scan kernels ----------------

__global__ __launch_bounds__(256) void scan_reduce(
    const int* __restrict__ deg, int* __restrict__ part, int N) {
    __shared__ int sh[256];
    int t = threadIdx.x, i = blockIdx.x * 256 + t;
    sh[t] = (i < N) ? deg[i] : 0;
    __syncthreads();
    for (int off = 128; off > 0; off >>= 1) {
        if (t < off) sh[t] += sh[t + off];
        __syncthreads();
    }
    if (t == 0) part[blockIdx.x] = sh[0];
}

__global__ __launch_bounds__(1024) void scan_part(int* __restrict__ part, int nb) {
    __shared__ int sh[1024];
    int t = threadIdx.x;
    int x = (t < nb) ? part[t] : 0;
    sh[t] = x;
    __syncthreads();
    for (int off = 1; off < 1024; off <<= 1) {
        int y = (t >= off) ? sh[t - off] : 0;
        __syncthreads();
        sh[t] += y;
        __syncthreads();
    }
    if (t < nb) part[t] = sh[t] - x;  // exclusive
}

__global__ __launch_bounds__(256) void scan_write(
    int* __restrict__ rowptr, const int* __restrict__ part, int N) {
    __shared__ int sh[256];
    int t = threadIdx.x, i = blockIdx.x * 256 + t;
    int x = (i < N) ? rowptr[i] : 0;
    sh[t] = x;
    __syncthreads();
    for (int off = 1; off < 256; off <<= 1) {
        int y = (t >= off) ? sh[t - off] : 0;
        __syncthreads();
        sh[t] += y;
        __syncthreads();
    }
    if (i < N) rowptr[i] = part[blockIdx.x] + sh[t] - x;  // exclusive scan
}

// After this, rowptr[v] = end(v); start(v) = (v ? rowptr[v-1] : 0).
// Slot payload: int2{ src | ety<<20 , bitcast(dot[src]) }.
__global__ __launch_bounds__(256) void scatter_edges(
    const int* __restrict__ src, const int* __restrict__ dst,
    const int* __restrict__ ety, const float* __restrict__ dot,
    int* __restrict__ rowptr, int2* __restrict__ spk2, int E) {
    int e = blockIdx.x * 256 + threadIdx.x;
    if (e < E) {
        int sv = src[e];
        int slot = atomicAdd(&rowptr[dst[e]], 1);
        spk2[slot] = make_int2(sv | (ety[e] << 20), __float_as_int(dot[sv]));
    }
}

// ------------- fused layer-0: att + softmax + message + bi-layer GEMV -------
// 32 lanes per dst node (8 nodes / 256-thread block): two 16-lane halves each
// walk half the node's edge list with a dual-edge pipeline + next-pair
// prefetch. DPP reductions; transposed weights staged in LDS.
__global__ __launch_bounds__(256) void fused_l0(
    const int* __restrict__ rowptr, const int2* __restrict__ spk2,
    const float* __restrict__ ent, const float* __restrict__ dot,
    const float* __restrict__ relE, const float* __restrict__ relT,
    const float* __restrict__ W1, const float* __restrict__ b1,
    const float* __restrict__ W2, const float* __restrict__ b2,
    float* __restrict__ exatt, float* __restrict__ sinv,
    float* __restrict__ node1raw, float* __restrict__ out, int N) {
    __shared__ float  al[8][64];
    __shared__ float  bl[8][64];
    __shared__ float  rT[16][64];    // rel tables (16 rels x 64)
    __shared__ float  rE[16][64];
    __shared__ float4 WtA[16 * 32];  // W1 transposed: [dd][j] = W1[4dd..4dd+3][j]
    __shared__ float4 WtB[16 * 32];
    int t = threadIdx.x;

    {   // stage rel tables + transposed weights (256 threads)
        int r = t >> 4, c = (t & 15) * 4;
        *(float4*)&rT[r][c] = *(const float4*)(relT + r * 64 + c);
        *(float4*)&rE[r][c] = *(const float4*)(relE + r * 64 + c);
        int j = t & 31;
        for (int dd = t >> 5; dd < 16; dd += 8) {
            int d4 = dd * 4;
            WtA[dd * 32 + j] = make_float4(W1[(d4+0)*32 + j], W1[(d4+1)*32 + j],
                                           W1[(d4+2)*32 + j], W1[(d4+3)*32 + j]);
            WtB[dd * 32 + j] = make_float4(W2[(d4+0)*32 + j], W2[(d4+1)*32 + j],
                                           W2[(d4+2)*32 + j], W2[(d4+3)*32 + j]);
        }
    }
    __syncthreads();  // the only block barrier

    int nv = t >> 5, half = (t >> 4) & 1, lane = t & 15;
    int v = blockIdx.x * 8 + nv;
    if (v >= N) return;

    int s = v ? rowptr[v - 1] : 0;
    int epos = rowptr[v];
    int deg = epos - s;
    int mid = s + ((deg + 1) >> 1);
    int hs   = half ? mid  : s;
    int hend = half ? epos : mid;

    const float4 he = *(const float4*)(ent + (size_t)v * 64 + lane * 4);
    float dh = dot[v];

    float4 macc = {0.f, 0.f, 0.f, 0.f};
    float sumex = 0.0f;

    for (int base = hs; base < hend; base += 16) {
        int rem = hend - base;
        int cnt = rem < 16 ? rem : 16;
        int2 ms = spk2[base + (lane < rem ? lane : rem - 1)];  // coalesced 8B
        float myex = 0.0f;

        int pk0 = __shfl(ms.x, 0, 16);
        int pk1 = __shfl(ms.x, cnt > 1 ? 1 : 0, 16);
        float sd0 = __int_as_float(__shfl(ms.y, 0, 16));
        float sd1 = __int_as_float(__shfl(ms.y, cnt > 1 ? 1 : 0, 16));
        float4 te0 = *(const float4*)(ent + (size_t)(pk0 & 0xFFFFF) * 64 + lane * 4);
        float4 te1 = *(const float4*)(ent + (size_t)(pk1 & 0xFFFFF) * 64 + lane * 4);

        for (int k = 0; k < cnt; k += 2) {
            float4 ta = te0, tb = te1;
            float  sa = sd0, sb = sd1;
            int rva = (pk0 >> 20) & 15;
            int rvb = (pk1 >> 20) & 15;
            bool hasb = (k + 1) < cnt;

            if (k + 2 < cnt) {  // prefetch next pair while computing this one
                int i2 = k + 2, i3 = (k + 3 < cnt) ? (k + 3) : (k + 2);
                pk0 = __shfl(ms.x, i2, 16);
                pk1 = __shfl(ms.x, i3, 16);
                sd0 = __int_as_float(__shfl(ms.y, i2, 16));
                sd1 = __int_as_float(__shfl(ms.y, i3, 16));
                te0 = *(const float4*)(ent + (size_t)(pk0 & 0xFFFFF) * 64 + lane * 4);
                te1 = *(const float4*)(ent + (size_t)(pk1 & 0xFFFFF) * 64 + lane * 4);
            }

            const float4 rpa = *(const float4*)&rT[rva][lane * 4];
            const float4 rea = *(const float4*)&rE[rva][lane * 4];
            const float4 rpb = *(const float4*)&rT[rvb][lane * 4];
            const float4 reb = *(const float4*)&rE[rvb][lane * 4];

            float4 mta, mha, mtb, mhb;
            mta.x = ta.x + sa * rpa.x; mta.y = ta.y + sa * rpa.y;
            mta.z = ta.z + sa * rpa.z; mta.w = ta.w + sa * rpa.w;
            mha.x = he.x + dh * rpa.x; mha.y = he.y + dh * rpa.y;
            mha.z = he.z + dh * rpa.z; mha.w = he.w + dh * rpa.w;
            mtb.x = tb.x + sb * rpb.x; mtb.y = tb.y + sb * rpb.y;
            mtb.z = tb.z + sb * rpb.z; mtb.w = tb.w + sb * rpb.w;
            mhb.x = he.x + dh * rpb.x; mhb.y = he.y + dh * rpb.y;
            mhb.z = he.z + dh * rpb.z; mhb.w = he.w + dh * rpb.w;

            float ssta = red16(mta.x*mta.x + mta.y*mta.y + mta.z*mta.z + mta.w*mta.w);
            float ssha = red16(mha.x*mha.x + mha.y*mha.y + mha.z*mha.z + mha.w*mha.w);
            float sstb = red16(mtb.x*mtb.x + mtb.y*mtb.y + mtb.z*mtb.z + mtb.w*mtb.w);
            float sshb = red16(mhb.x*mhb.x + mhb.y*mhb.y + mhb.z*mhb.z + mhb.w*mhb.w);
            float ita = inv_norm(ssta), iha = inv_norm(ssha);
            float itb = inv_norm(sstb), ihb = inv_norm(sshb);

            float txa = fast_tanh(mha.x * iha + rea.x);
            float tya = fast_tanh(mha.y * iha + rea.y);
            float tza = fast_tanh(mha.z * iha + rea.z);
            float twa = fast_tanh(mha.w * iha + rea.w);
            float txb = fast_tanh(mhb.x * ihb + reb.x);
            float tyb = fast_tanh(mhb.y * ihb + reb.y);
            float tzb = fast_tanh(mhb.z * ihb + reb.z);
            float twb = fast_tanh(mhb.w * ihb + reb.w);

            float atta = ita * red16(mta.x*txa + mta.y*tya + mta.z*tza + mta.w*twa);
            float attb = itb * red16(mtb.x*txb + mtb.y*tyb + mtb.z*tzb + mtb.w*twb);

            // softmax shift-invariant; |att| <= 8 so exp is safe without max-sub
            float exa  = __builtin_amdgcn_exp2f(atta * LOG2E);
            float exbR = __builtin_amdgcn_exp2f(attb * LOG2E);
            float exb  = hasb ? exbR : 0.0f;

            // lane k captures its edge's raw ex; stored coalesced per chunk
            myex = (lane == k) ? exa : myex;
            myex = (lane == k + 1) ? exbR : myex;

            sumex += exa + exb;
            macc.x += exa * ta.x + exb * tb.x;
            macc.y += exa * ta.y + exb * tb.y;
            macc.z += exa * ta.z + exb * tb.z;
            macc.w += exa * ta.w + exb * tb.w;
        }
        if (lane < cnt) exatt[base + lane] = myex;
    }

    // combine the two halves of this node (width-32 xor-by-16)
    sumex  += __shfl_xor(sumex,  16, 32);
    macc.x += __shfl_xor(macc.x, 16, 32);
    macc.y += __shfl_xor(macc.y, 16, 32);
    macc.z += __shfl_xor(macc.z, 16, 32);
    macc.w += __shfl_xor(macc.w, 16, 32);

    float inv = 1.0f / fmaxf(sumex, EPSF);
    if ((t & 31) == 0) sinv[v] = inv;
    macc.x *= inv; macc.y *= inv; macc.z *= inv; macc.w *= inv;

    if (!half) {
        // out cols 0..63 = ent_embed
        *(float4*)(out + (size_t)v * 112 + lane * 4) = he;
        float4 av, bv;
        av.x = he.x + macc.x; av.y = he.y + macc.y;
        av.z = he.z + macc.z; av.w = he.w + macc.w;
        bv.x = he.x * macc.x; bv.y = he.y * macc.y;
        bv.z = he.z * macc.z; bv.w = he.w * macc.w;
        *(float4*)&al[nv][lane * 4] = av;
        *(float4*)&bl[nv][lane * 4] = bv;
    }
    // no __syncthreads: writers and readers are the same wave (program order)

    int j = t & 31;
    float acc1 = b1[j], acc2 = b2[j];
    #pragma unroll
    for (int dd = 0; dd < 16; ++dd) {
        float4 a4 = *(const float4*)&al[nv][dd * 4];   // broadcast read
        float4 b4 = *(const float4*)&bl[nv][dd * 4];
        float4 wa = WtA[dd * 32 + j];                  // coalesced b128
        float4 wb = WtB[dd * 32 + j];
        acc1 += a4.x*wa.x + a4.y*wa.y + a4.z*wa.z + a4.w*wa.w;
        acc2 += b4.x*wb.x + b4.y*wb.y + b4.z*wb.z + b4.w*wb.w;
    }
    node1raw[(size_t)v * 32 + j] = leaky(acc1) + leaky(acc2);
}

// ------------- fused layer-1: message gather + bi-layer GEMV + norms --------
// 16 lanes per node (16 nodes / block): two 8-lane halves, dual-edge pipeline.
__global__ __launch_bounds__(256) void fused_l1(
    const int* __restrict__ rowptr, const int2* __restrict__ spk2,
    const float* __restrict__ exatt, const float* __restrict__ sinv,
    const float* __restrict__ node1raw,
    const float* __restrict__ W1, const float* __restrict__ b1,
    const float* __restrict__ W2, const float* __restrict__ b2,
    float* __restrict__ out, int N) {
    __shared__ float  A[16][32];
    __shared__ float  B[16][32];
    __shared__ float4 WtC[8 * 16];  // W1 transposed: [dd][j] = W1[4dd..4dd+3][j]
    __shared__ float4 WtD[8 * 16];
    int t = threadIdx.x;

    {   // stage transposed weights (first 128 threads W1, next 128 W2)
        int tt = t & 127;
        int j = tt & 15, dd = tt >> 4;  // dd 0..7
        int d4 = dd * 4;
        const float* W = (t < 128) ? W1 : W2;
        float4* Wt = (t < 128) ? WtC : WtD;
        Wt[dd * 16 + j] = make_float4(W[(d4+0)*16 + j], W[(d4+1)*16 + j],
                                      W[(d4+2)*16 + j], W[(d4+3)*16 + j]);
    }
    __syncthreads();

    int nv = t >> 4, half = (t >> 3) & 1, lane = t & 7;
    int v = blockIdx.x * 16 + nv;
    if (v >= N) return;

    int s = v ? rowptr[v - 1] : 0;
    int epos = rowptr[v];
    int deg = epos - s;
    int mid = s + ((deg + 1) >> 1);
    int hs   = half ? mid  : s;
    int hend = half ? epos : mid;

    float4 n = *(const float4*)(node1raw + (size_t)v * 32 + lane * 4);
    float4 acc = {0.f, 0.f, 0.f, 0.f};

    for (int base = hs; base < hend; base += 8) {
        int rem = hend - base;
        int cnt = rem < 8 ? rem : 8;
        int idx = base + (lane < rem ? lane : rem - 1);
        int   mypk = spk2[idx].x;
        float myex = exatt[idx];

        int pk0 = __shfl(mypk, 0, 8);
        int pk1 = __shfl(mypk, cnt > 1 ? 1 : 0, 8);
        float4 x0 = *(const float4*)(node1raw + (size_t)(pk0 & 0xFFFFF) * 32 + lane * 4);
        float4 x1 = *(const float4*)(node1raw + (size_t)(pk1 & 0xFFFFF) * 32 + lane * 4);

        for (int k = 0; k < cnt; k += 2) {
            float4 xa = x0, xb = x1;
            float aa = __shfl(myex, k, 8);
            float ab = __shfl(myex, (k + 1 < cnt) ? (k + 1) : k, 8);
            if (!((k + 1) < cnt)) ab = 0.0f;

            if (k + 2 < cnt) {
                pk0 = __shfl(mypk, k + 2, 8);
                pk1 = __shfl(mypk, (k + 3 < cnt) ? (k + 3) : (k + 2), 8);
                x0 = *(const float4*)(node1raw + (size_t)(pk0 & 0xFFFFF) * 32 + lane * 4);
                x1 = *(const float4*)(node1raw + (size_t)(pk1 & 0xFFFFF) * 32 + lane * 4);
            }
            acc.x += aa * xa.x + ab * xb.x;
            acc.y += aa * xa.y + ab * xb.y;
            acc.z += aa * xa.z + ab * xb.z;
            acc.w += aa * xa.w + ab * xb.w;
        }
    }
    // combine halves (lane^8 within 16, via DPP row_ror:8)
    acc.x = xor8add(acc.x);
    acc.y = xor8add(acc.y);
    acc.z = xor8add(acc.z);
    acc.w = xor8add(acc.w);

    float inv = sinv[v];
    acc.x *= inv; acc.y *= inv; acc.z *= inv; acc.w *= inv;

    float ss = red8(n.x*n.x + n.y*n.y + n.z*n.z + n.w*n.w);
    float inv1 = inv_norm(ss);

    if (!half) {
        float4 nn = {n.x*inv1, n.y*inv1, n.z*inv1, n.w*inv1};
        *(float4*)(out + (size_t)v * 112 + 64 + lane * 4) = nn;
        float4 av = {n.x + acc.x, n.y + acc.y, n.z + acc.z, n.w + acc.w};
        float4 bv = {n.x * acc.x, n.y * acc.y, n.z * acc.z, n.w * acc.w};
        *(float4*)&A[nv][lane * 4] = av;
        *(float4*)&B[nv][lane * 4] = bv;
    }
    // no __syncthreads: writers and readers are the same wave (program order)

    int j = t & 15;
    float a1 = b1[j], a2 = b2[j];
    #pragma unroll
    for (int dd = 0; dd < 8; ++dd) {
        float4 a4 = *(const float4*)&A[nv][dd * 4];   // broadcast read
        float4 b4 = *(const float4*)&B[nv][dd * 4];
        float4 wc = WtC[dd * 16 + j];
        float4 wd = WtD[dd * 16 + j];
        a1 += a4.x*wc.x + a4.y*wc.y + a4.z*wc.z + a4.w*wc.w;
        a2 += b4.x*wd.x + b4.y*wd.y + b4.z*wd.z + b4.w*wd.w;
    }
    float tot = leaky(a1) + leaky(a2);
    float s2 = red16(tot * tot);
    float inv2 = inv_norm(s2);
    out[(size_t)v * 112 + 96 + j] = tot * inv2;  // cols 96..111
}

extern "C" void kernel_launch(void* const* d_in, const int* in_sizes, int n_in,
                              void* d_out, int out_size, void* d_ws, size_t ws_size,
                              hipStream_t stream) {
    const int*   src  = (const int*)d_in[0];
    const int*   dst  = (const int*)d_in[1];
    const int*   ety  = (const int*)d_in[2];
    const float* ent  = (const float*)d_in[3];
    const float* entT = (const float*)d_in[4];
    const float* relE = (const float*)d_in[5];
    const float* relT = (const float*)d_in[6];
    const float* W1_0 = (const float*)d_in[7];
    const float* b1_0 = (const float*)d_in[8];
    const float* W2_0 = (const float*)d_in[9];
    const float* b2_0 = (const float*)d_in[10];
    const float* W1_1 = (const float*)d_in[11];
    const float* b1_1 = (const float*)d_in[12];
    const float* W2_1 = (const float*)d_in[13];
    const float* b2_1 = (const float*)d_in[14];
    float* out = (float*)d_out;

    const int E = in_sizes[0];
    const int N = in_sizes[3] / 64;
    const int nb = (N + 255) / 256;  // scan blocks (must be <= 1024)

    auto al256 = [](size_t x) { return (x + 255) & ~(size_t)255; };
    char* ws = (char*)d_ws;
    size_t offExatt = 0;
    size_t offS     = al256(offExatt + (size_t)E * 4);
    size_t offDot   = al256(offS + (size_t)N * 4);
    size_t offRow   = al256(offDot + (size_t)N * 4);
    size_t offSpk   = al256(offRow + (size_t)N * 4);
    size_t offPart  = al256(offSpk + (size_t)E * 8);
    size_t offN1    = al256(offPart + (size_t)nb * 4);
    float* exatt    = (float*)(ws + offExatt);
    float* sinv     = (float*)(ws + offS);
    float* dot      = (float*)(ws + offDot);
    int*   rowptr   = (int*)(ws + offRow);
    int2*  spk2     = (int2*)(ws + offSpk);
    int*   part     = (int*)(ws + offPart);
    float* node1raw = (float*)(ws + offN1);   // [N,32]

    // ---- CSR build + per-node dot ----
    hipMemsetAsync(rowptr, 0, (size_t)N * 4, stream);
    int N16 = N * 16;
    prep<<<(N16 + E + 255) / 256, 256, 0, stream>>>(ent, entT, dot, dst,
                                                    rowptr, N16, E);
    scan_reduce<<<nb, 256, 0, stream>>>(rowptr, part, N);
    scan_part<<<1, 1024, 0, stream>>>(part, nb);
    scan_write<<<nb, 256, 0, stream>>>(rowptr, part, N);
    int blkE = (E + 255) / 256;
    scatter_edges<<<blkE, 256, 0, stream>>>(src, dst, ety, dot, rowptr, spk2, E);

    // ---- fused layer 0: attention + softmax + message + node update ----
    fused_l0<<<(N + 7) / 8, 256, 0, stream>>>(
        rowptr, spk2, ent, dot, relE, relT,
        W1_0, b1_0, W2_0, b2_0, exatt, sinv, node1raw, out, N);

    // ---- fused layer 1: message + node update + norms ----
    fused_l1<<<(N + 15) / 16, 256, 0, stream>>>(
        rowptr, spk2, exatt, sinv, node1raw,
        W1_1, b1_1, W2_1, b2_1, out, N);
}